// Round 15
// baseline (849.068 us; speedup 1.0000x reference)
//
#include <hip/hip_runtime.h>
#include <hip/hip_bf16.h>

typedef __hip_bfloat16 bf16;
typedef short short4_t __attribute__((ext_vector_type(4)));
typedef short short8 __attribute__((ext_vector_type(8)));
typedef float f32x4 __attribute__((ext_vector_type(4)));

// static config
#define DIMC 512
#define HEADS_ 16
#define NTOK 65        // 64 window tokens + 1 time token
#define NWIN 64
#define NB 16
#define HID 2048
#define TOTROWS 66560  // 16*64*65
#define IMGROWS 65536  // 16*4096
#define ATT_CHUNK_WB 128
#define ATT_CHUNK_ROWS (ATT_CHUNK_WB * NTOK)  // 8320

// ---------------- helpers ----------------

__device__ __forceinline__ float b2f(short s) {
  unsigned int u = ((unsigned int)(unsigned short)s) << 16;
  float f; __builtin_memcpy(&f, &u, 4); return f;
}
__device__ __forceinline__ short f2s(float f) {
  bf16 b = __float2bfloat16(f);
  short s; __builtin_memcpy(&s, &b, 2); return s;
}

// async global->LDS, 16B per lane; LDS dest is wave-uniform base + lane*16
__device__ __forceinline__ void async_lds16(const bf16* g, bf16* l) {
  __builtin_amdgcn_global_load_lds(
      (const __attribute__((address_space(1))) unsigned int*)g,
      (__attribute__((address_space(3))) unsigned int*)l,
      16, 0, 0);
}

// per-wave LN stats over 512 elems (8 per lane)
__device__ __forceinline__ void wave_stats512(const float* v, float& m, float& rstd)
{
  float s = 0.0f, ss = 0.0f;
  #pragma unroll
  for (int e = 0; e < 8; ++e) { s += v[e]; ss += v[e] * v[e]; }
  #pragma unroll
  for (int o = 1; o < 64; o <<= 1) { s += __shfl_xor(s, o); ss += __shfl_xor(ss, o); }
  m = s * (1.0f / 512.0f);
  rstd = rsqrtf(ss * (1.0f / 512.0f) - m * m + 1e-5f);
}

// 8-op tanh-form GELU via sigmoid identity; max abs err ~3e-4
__device__ __forceinline__ float gelu_t(float v) {
  float v2 = v * v;
  float a  = fmaf(0.044715f, v2, 1.0f);
  float e  = __builtin_exp2f(-2.3022042f * (v * a));   // exp(-2z)
  return v * __builtin_amdgcn_rcpf(1.0f + e);
}

// ---------------- small kernels ----------------

__global__ __launch_bounds__(256) void time_emb_kernel(
    const float* __restrict__ emb, const float* __restrict__ W_emb,
    const float* __restrict__ b_emb, float* __restrict__ t)
{
  int b = blockIdx.x;
  int c = blockIdx.y * 256 + threadIdx.x;
  __shared__ float se[512];
  for (int k = threadIdx.x; k < 512; k += 256) {
    float e = emb[b * 512 + k];
    se[k] = e / (1.0f + expf(-e));
  }
  __syncthreads();
  float acc = b_emb[c];
  for (int k = 0; k < 512; ++k) acc += se[k] * W_emb[k * 512 + c];
  t[b * 512 + c] = acc;
}

// W (Kd x Nd) f32 -> Wt (Nd x Kd) bf16
__global__ void transpose_cast_kernel(const float* __restrict__ W, bf16* __restrict__ Wt,
                                      int Kd, int Nd)
{
  __shared__ float tile[32][33];
  int n0 = blockIdx.x * 32, k0 = blockIdx.y * 32;
  for (int r = threadIdx.y; r < 32; r += 8)
    tile[r][threadIdx.x] = W[(long)(k0 + r) * Nd + n0 + threadIdx.x];
  __syncthreads();
  for (int r = threadIdx.y; r < 32; r += 8)
    Wt[(long)(n0 + r) * Kd + k0 + threadIdx.x] = __float2bfloat16(tile[threadIdx.x][r]);
}

// combined bias+mask table: tbl[h][wtype][i(query) 80][t(key) 80] f32
__global__ __launch_bounds__(256) void bias_mask_kernel(
    const float* __restrict__ btab, float* __restrict__ tbl)
{
  int h = blockIdx.x, wt = blockIdx.y;
  for (int idx = threadIdx.x; idx < 6400; idx += 256) {
    int i = idx / 80, t = idx % 80;
    float v;
    if (t >= 65) v = -1e30f;
    else if (i >= 64 || t == 64) v = 0.0f;
    else {
      int rel = (((i >> 3) - (t >> 3) + 7) * 15) + ((i & 7) - (t & 7) + 7);
      v = btab[rel * HEADS_ + h];
      int rci = (wt & 2) ? (((i >> 3) < 4) ? 1 : 2) : 0;
      int cci = (wt & 1) ? (((i & 7) < 4) ? 1 : 2) : 0;
      int rct = (wt & 2) ? (((t >> 3) < 4) ? 1 : 2) : 0;
      int cct = (wt & 1) ? (((t & 7) < 4) ? 1 : 2) : 0;
      if (rci * 3 + cci != rct * 3 + cct) v -= 100.0f;
    }
    tbl[(h * 4 + wt) * 6400 + idx] = v;
  }
}

// LN1 + shift + window partition + time-token append -> xw bf16 (66560 x 512);
// also emits xb = bf16(x) at the SOURCE pixel (bijective coverage).
__global__ __launch_bounds__(256) void ln1_window_kernel(
    const float* __restrict__ x, const float* __restrict__ gamma,
    const float* __restrict__ beta, const float* __restrict__ t,
    bf16* __restrict__ xw, bf16* __restrict__ xb)
{
  long r = (long)blockIdx.x * 4 + (threadIdx.x >> 6);   // 0..66559
  int lane = threadIdx.x & 63;
  int wb = (int)(r / NTOK), i = (int)(r % NTOK);
  int b = wb >> 6, w = wb & 63;
  bf16* out = xw + r * 512 + lane * 8;
  if (i == 64) {
    const float* tr = t + b * 512 + lane * 8;
    short8 o;
    #pragma unroll
    for (int e = 0; e < 8; ++e) o[e] = f2s(tr[e]);
    *(short8*)out = o;
    return;
  }
  int wh = w >> 3, ww = w & 7, ih = i >> 3, iw = i & 7;
  int hsrc = ((wh * 8 + ih) + 4) & 63;
  int wsrc = ((ww * 8 + iw) + 4) & 63;
  long src = (long)b * 4096 + hsrc * 64 + wsrc;
  const float* xr = x + src * 512 + lane * 8;
  float v[8];
  *(f32x4*)&v[0] = *(const f32x4*)xr;
  *(f32x4*)&v[4] = *(const f32x4*)(xr + 4);
  short8 xo;
  #pragma unroll
  for (int e = 0; e < 8; ++e) xo[e] = f2s(v[e]);
  *(short8*)(xb + src * 512 + lane * 8) = xo;     // raw shortcut in bf16
  float m, rstd;
  wave_stats512(v, m, rstd);
  const float* g = gamma + lane * 8;
  const float* bt = beta + lane * 8;
  short8 o;
  #pragma unroll
  for (int e = 0; e < 8; ++e) o[e] = f2s((v[e] - m) * rstd * g[e] + bt[e]);
  *(short8*)out = o;
}

// LN2 over x1b rows (bf16 in, bf16 out); one WAVE per row
__global__ __launch_bounds__(256) void ln2_kernel(
    const bf16* __restrict__ x1, const float* __restrict__ gamma,
    const float* __restrict__ beta, bf16* __restrict__ out)
{
  long r = (long)blockIdx.x * 4 + (threadIdx.x >> 6);
  int lane = threadIdx.x & 63;
  short8 xv = *(const short8*)(x1 + r * 512 + lane * 8);
  float v[8];
  #pragma unroll
  for (int e = 0; e < 8; ++e) v[e] = b2f(xv[e]);
  float m, rstd;
  wave_stats512(v, m, rstd);
  const float* g = gamma + lane * 8;
  const float* bt = beta + lane * 8;
  short8 o;
  #pragma unroll
  for (int e = 0; e < 8; ++e) o[e] = f2s((v[e] - m) * rstd * g[e] + bt[e]);
  *(short8*)(out + r * 512 + lane * 8) = o;
}

// ---------------- 128x128 MFMA GEMM, BK=32, 3-buffer counted-vmcnt, 3 blk/CU --
// 256 threads = 4 waves (2M x 2N), each 64x64. LDS 48 KiB (3+3 bufs).
// Depth-2 prefetch, vmcnt(4) counted wait, triplet-peeled compile-time buffers.
// ALL epilogues go through a 64x132 f32 LDS transpose (bias/gelu applied at
// frag-write), then vectorized row-major global I/O:
// EPI 0: bf16 store (qkv) | 1: gelu->bf16 (mlp1)
// EPI 2: proj: x1b = bf16(xb + C) (all bf16) | 3: mlp2: out = float(x1b) + C (f32)
template<int EPI, int K>
__global__ __launch_bounds__(256, 3) void gemmk_kernel(
    const bf16* __restrict__ A, const bf16* __restrict__ Bt,
    const float* __restrict__ bias, int N, int nx,
    bf16* __restrict__ outB, float* __restrict__ outF,
    const bf16* __restrict__ xinB, int rowOffset)
{
  constexpr int NKT = K / 32;
  static_assert((NKT - 1) % 3 == 0, "triplet peel needs NKT = 3m+1");
  __shared__ bf16 ldsbuf[6 * 128 * 32];          // lA: 3 bufs, lB: 3 bufs
  bf16* const lAp = ldsbuf;
  bf16* const lBp = ldsbuf + 3 * 4096;
  const int tid = threadIdx.x;
  const int lane = tid & 63, wv = tid >> 6;  // 4 waves
  const int wm = wv >> 1, wn = wv & 1;       // 2 x 2
  const int fr = lane & 15, fg = lane >> 4;

  // bijective XCD swizzle (m204)
  const int nwg = gridDim.x, bid = blockIdx.x;
  const int q8 = nwg >> 3, rr8 = nwg & 7;
  const int xcd = bid & 7, idx = bid >> 3;
  const int sid = (xcd < rr8 ? xcd * (q8 + 1) : rr8 * (q8 + 1) + (xcd - rr8) * q8) + idx;
  const long row0 = (long)(sid / nx) * 128;
  const long col0 = (long)(sid % nx) * 128;

  // staging: one 16B slot per lane; one wave-instr covers 16 rows (64B rows)
  const int rl = lane >> 2, sp = lane & 3;
  const int s = sp ^ ((rl >> 1) & 3);        // pre-swizzled global slot
  const bf16* ga0 = A  + (row0 + wv * 32 + rl) * (long)K + s * 8;
  const bf16* ga1 = ga0 + 16 * (long)K;
  const bf16* gb0 = Bt + (col0 + wv * 32 + rl) * (long)K + s * 8;
  const bf16* gb1 = gb0 + 16 * (long)K;

  f32x4 acc[4][4] = {};
  const int swr = (fg ^ ((fr >> 1) & 3)) << 4;   // read-side swizzled slot byte

  auto stage = [&](int buf, int t) {
    const long o = (long)t * 32;
    async_lds16(ga0 + o, &lAp[buf * 4096 + (wv * 32) * 32]);
    async_lds16(ga1 + o, &lAp[buf * 4096 + (wv * 32 + 16) * 32]);
    async_lds16(gb0 + o, &lBp[buf * 4096 + (wv * 32) * 32]);
    async_lds16(gb1 + o, &lBp[buf * 4096 + (wv * 32 + 16) * 32]);
  };

  stage(0, 0);
  stage(1, 1);

#define GBODY(BUF)                                                              \
  do {                                                                          \
    if (t + 1 < NKT) asm volatile("s_waitcnt vmcnt(4)" ::: "memory");           \
    else             asm volatile("s_waitcnt vmcnt(0)" ::: "memory");           \
    __builtin_amdgcn_s_barrier();                                               \
    short8 bfv[4], af[4];                                                       \
    _Pragma("unroll")                                                           \
    for (int ni = 0; ni < 4; ++ni)                                              \
      bfv[ni] = *(const short8*)((const char*)&lBp[(BUF) * 4096] +              \
                                 (wn * 64 + ni * 16 + fr) * 64 + swr);          \
    _Pragma("unroll")                                                           \
    for (int mi = 0; mi < 4; ++mi)                                              \
      af[mi] = *(const short8*)((const char*)&lAp[(BUF) * 4096] +               \
                                (wm * 64 + mi * 16 + fr) * 64 + swr);           \
    if (t + 2 < NKT) stage(((BUF) + 2) % 3, t + 2);                             \
    __builtin_amdgcn_s_setprio(1);                                              \
    _Pragma("unroll")                                                           \
    for (int mi = 0; mi < 4; ++mi)                                              \
      _Pragma("unroll")                                                         \
      for (int ni = 0; ni < 4; ++ni)                                            \
        acc[mi][ni] = __builtin_amdgcn_mfma_f32_16x16x32_bf16(                  \
            af[mi], bfv[ni], acc[mi][ni], 0, 0, 0);                             \
    __builtin_amdgcn_s_setprio(0);                                              \
    ++t;                                                                        \
  } while (0)

  int t = 0;
  GBODY(0);                                     // t = 0 (buf 0)
  for (int g = 0; g < (NKT - 1) / 3; ++g) {     // triplets with fixed bufs
    GBODY(1);
    GBODY(2);
    GBODY(0);
  }
#undef GBODY

  // ---- unified LDS-transposed epilogue ----
  __syncthreads();                       // all frag reads done; LDS reusable
  float* ep = (float*)ldsbuf;            // 64*132*4 = 33.8 KB (< 48 KB)
  float bs[4];
  #pragma unroll
  for (int ni = 0; ni < 4; ++ni) bs[ni] = bias[col0 + wn * 64 + ni * 16 + fr];
  const int l31 = lane & 31, lr2 = lane >> 5;   // f32-path lane split
  const int c16 = tid & 15, r16 = tid >> 4;     // bf16-path lane split
  #pragma unroll
  for (int h = 0; h < 2; ++h) {
    if (wm == h) {
      #pragma unroll
      for (int mi = 0; mi < 4; ++mi)
        #pragma unroll
        for (int ni = 0; ni < 4; ++ni)
          #pragma unroll
          for (int j = 0; j < 4; ++j) {
            float v = acc[mi][ni][j] + bs[ni];
            if (EPI == 1) v = gelu_t(v);
            ep[(mi * 16 + fg * 4 + j) * 132 + wn * 64 + ni * 16 + fr] = v;
          }
    }
    __syncthreads();
    if (EPI == 0 || EPI == 1) {
      // 16 threads/row, short8 16B coalesced stores
      #pragma unroll
      for (int it = 0; it < 4; ++it) {
        int lrow = it * 16 + r16;
        f32x4 a = *(const f32x4*)&ep[lrow * 132 + c16 * 8];
        f32x4 bq = *(const f32x4*)&ep[lrow * 132 + c16 * 8 + 4];
        short8 o8;
        #pragma unroll
        for (int e = 0; e < 4; ++e) { o8[e] = f2s(a[e]); o8[4 + e] = f2s(bq[e]); }
        *(short8*)&outB[(row0 + h * 64 + lrow) * N + col0 + c16 * 8] = o8;
      }
    } else {
      #pragma unroll
      for (int it = 0; it < 8; ++it) {
        int lrow = it * 8 + wv * 2 + lr2;
        long rr = row0 + h * 64 + lrow;
        f32x4 v = *(const f32x4*)&ep[lrow * 132 + l31 * 4];
        if (EPI == 2) {
          int grow = rowOffset + (int)rr;
          int ii = grow % NTOK;
          if (ii != 64) {
            int wb = grow / NTOK;
            int b = wb >> 6, w = wb & 63;
            int wh = w >> 3, ww = w & 7, ih = ii >> 3, iw = ii & 7;
            int hh   = ((wh * 8 + ih) + 4) & 63;
            int wcol = ((ww * 8 + iw) + 4) & 63;
            long o = ((long)b * 4096 + hh * 64 + wcol) * 512 + col0 + l31 * 4;
            short4_t xv = *(const short4_t*)&xinB[o];
            short4_t s4;
            #pragma unroll
            for (int e = 0; e < 4; ++e) s4[e] = f2s(b2f(xv[e]) + v[e]);
            *(short4_t*)&outB[o] = s4;     // x1b (bf16)
          }
        } else {                            // EPI 3
          long o = rr * N + col0 + l31 * 4;
          short4_t xv = *(const short4_t*)&xinB[o];
          f32x4 xf;
          #pragma unroll
          for (int e = 0; e < 4; ++e) xf[e] = b2f(xv[e]);
          *(f32x4*)&outF[o] = xf + v;      // final out (f32)
        }
      }
    }
    __syncthreads();
  }
}

// ---------------- MFMA windowed attention: one wave per (window-batch, head) ----
__global__ __launch_bounds__(64, 2) void attn_mfma_kernel(
    const bf16* __restrict__ qkv, bf16* __restrict__ attnO,
    const float* __restrict__ tbl, int wb0)
{
  __shared__ bf16 P[80 * 104];
  const int lwb = blockIdx.x, h = blockIdx.y;
  const int lane = threadIdx.x;
  const int fr = lane & 15, g = lane >> 4;
  const float scale = 0.17677669529663687f;   // 1/sqrt(32)
  const bf16* base = qkv + (long)lwb * 65 * 1536 + h * 32 + g * 8;

  // zero P pad slots (t in [80,104))
  for (int idx = lane; idx < 240; idx += 64) {
    int i = idx / 3, sl = idx % 3;
    *(short8*)&P[i * 104 + 80 + sl * 8] = (short8){0, 0, 0, 0, 0, 0, 0, 0};
  }

  short8 bq[5];
  #pragma unroll
  for (int tn = 0; tn < 5; ++tn) {
    int qr = tn * 16 + fr; qr = qr > 64 ? 64 : qr;
    bq[tn] = *(const short8*)(base + (long)qr * 1536);
  }

  f32x4 acc[5][5];
  #pragma unroll
  for (int tm = 0; tm < 5; ++tm) {
    int kr = tm * 16 + fr; kr = kr > 64 ? 64 : kr;
    short8 ak = *(const short8*)(base + 512 + (long)kr * 1536);
    #pragma unroll
    for (int tn = 0; tn < 5; ++tn)
      acc[tm][tn] = __builtin_amdgcn_mfma_f32_16x16x32_bf16(
          ak, bq[tn], (f32x4){0.0f, 0.0f, 0.0f, 0.0f}, 0, 0, 0);
  }

  const int w = (wb0 + lwb) & 63;
  const int wt = (((w >> 3) == 7) ? 2 : 0) + (((w & 7) == 7) ? 1 : 0);
  const float* tp = tbl + (h * 4 + wt) * 6400;
  #pragma unroll
  for (int tn = 0; tn < 5; ++tn) {
    const int i = tn * 16 + fr;
    const float* ti = tp + i * 80 + g * 4;
    float m = -3.0e38f;
    #pragma unroll
    for (int tm = 0; tm < 5; ++tm) {
      f32x4 bv = *(const f32x4*)(ti + tm * 16);
      #pragma unroll
      for (int r = 0; r < 4; ++r) {
        float sv = fmaf(acc[tm][tn][r], scale, bv[r]);
        acc[tm][tn][r] = sv;
        m = fmaxf(m, sv);
      }
    }
    m = fmaxf(m, __shfl_xor(m, 16));
    m = fmaxf(m, __shfl_xor(m, 32));
    float l = 0.0f;
    #pragma unroll
    for (int tm = 0; tm < 5; ++tm)
      #pragma unroll
      for (int r = 0; r < 4; ++r) {
        float e = __expf(acc[tm][tn][r] - m);
        acc[tm][tn][r] = e;
        l += e;
      }
    l += __shfl_xor(l, 16);
    l += __shfl_xor(l, 32);
    float inv = 1.0f / l;
    #pragma unroll
    for (int tm = 0; tm < 5; ++tm) {
      short4_t pk;
      #pragma unroll
      for (int r = 0; r < 4; ++r) pk[r] = f2s(acc[tm][tn][r] * inv);
      *(short4_t*)&P[i * 104 + tm * 16 + g * 4] = pk;
    }
  }

  const bf16* vbase = qkv + (long)lwb * 65 * 1536 + 1024 + h * 32;
  f32x4 oacc[2][5] = {};
  #pragma unroll
  for (int kt = 0; kt < 3; ++kt) {
    short8 bp[5];
    #pragma unroll
    for (int tn = 0; tn < 5; ++tn)
      bp[tn] = *(const short8*)&P[(tn * 16 + fr) * 104 + kt * 32 + g * 8];
    #pragma unroll
    for (int ma = 0; ma < 2; ++ma) {
      short8 av;
      #pragma unroll
      for (int e = 0; e < 8; ++e) {
        int vr = kt * 32 + g * 8 + e; vr = vr > 64 ? 64 : vr;
        av[e] = *(const short*)(vbase + (long)vr * 1536 + ma * 16 + fr);
      }
      #pragma unroll
      for (int tn = 0; tn < 5; ++tn)
        oacc[ma][tn] = __builtin_amdgcn_mfma_f32_16x16x32_bf16(
            av, bp[tn], oacc[ma][tn], 0, 0, 0);
    }
  }

  #pragma unroll
  for (int tn = 0; tn < 5; ++tn) {
    int i = tn * 16 + fr;
    if (i < 65) {
      bf16* op = attnO + (long)(lwb * 65 + i) * 512 + h * 32 + g * 4;
      #pragma unroll
      for (int ma = 0; ma < 2; ++ma) {
        short4_t o4;
        #pragma unroll
        for (int r = 0; r < 4; ++r) o4[r] = f2s(oacc[ma][tn][r]);
        *(short4_t*)(op + ma * 16) = o4;
      }
    }
  }
}

// ---------------- host ----------------

extern "C" void kernel_launch(void* const* d_in, const int* in_sizes, int n_in,
                              void* d_out, int out_size, void* d_ws, size_t ws_size,
                              hipStream_t stream)
{
  const float* x      = (const float*)d_in[0];
  const float* emb    = (const float*)d_in[1];
  const float* gamma1 = (const float*)d_in[2];
  const float* beta1  = (const float*)d_in[3];
  const float* W_emb  = (const float*)d_in[4];
  const float* b_emb  = (const float*)d_in[5];
  const float* W_qkv  = (const float*)d_in[6];
  const float* b_qkv  = (const float*)d_in[7];
  const float* btab   = (const float*)d_in[8];
  const float* W_proj = (const float*)d_in[9];
  const float* b_proj = (const float*)d_in[10];
  const float* gamma2 = (const float*)d_in[11];
  const float* beta2  = (const float*)d_in[12];
  const float* W1     = (const float*)d_in[13];
  const float* b1     = (const float*)d_in[14];
  const float* W2     = (const float*)d_in[15];
  const float* b2     = (const float*)d_in[16];
  float* out = (float*)d_out;
  (void)n_in; (void)in_sizes; (void)out_size;

  // xb (raw shortcut in bf16, 65536x512 = 67 MB) lives in the first half of
  // d_out: out is not written until mlp2, and xb's last read (proj) precedes it.
  bf16* xb = (bf16*)out;

  char* ws = (char*)d_ws;
  size_t off = 0;
  auto alloc = [&](size_t bytes) -> char* {
    char* p = ws + off;
    off += (bytes + 255) & ~(size_t)255;
    return p;
  };
  bf16* wt_qkv  = (bf16*)alloc((size_t)1536 * 512 * 2);
  bf16* wt_proj = (bf16*)alloc((size_t)512 * 512 * 2);
  bf16* wt1     = (bf16*)alloc((size_t)2048 * 512 * 2);
  bf16* wt2     = (bf16*)alloc((size_t)512 * 2048 * 2);
  float* tvec   = (float*)alloc((size_t)16 * 512 * 4);
  float* tbl    = (float*)alloc((size_t)16 * 4 * 6400 * 4);

  const size_t sz_xw    = (size_t)TOTROWS * 512 * 2;
  const size_t sz_qkv   = (size_t)TOTROWS * 1536 * 2;   // 204 MB
  const size_t sz_attnO = (size_t)TOTROWS * 512 * 2;
  const bool big = ws_size >= off + sz_xw + sz_qkv + sz_attnO + (4u << 20);

  // weight prep (common)
  transpose_cast_kernel<<<dim3(1536 / 32, 512 / 32), dim3(32, 8), 0, stream>>>(W_qkv, wt_qkv, 512, 1536);
  transpose_cast_kernel<<<dim3(512 / 32, 512 / 32),  dim3(32, 8), 0, stream>>>(W_proj, wt_proj, 512, 512);
  transpose_cast_kernel<<<dim3(2048 / 32, 512 / 32), dim3(32, 8), 0, stream>>>(W1, wt1, 512, 2048);
  transpose_cast_kernel<<<dim3(512 / 32, 2048 / 32), dim3(32, 8), 0, stream>>>(W2, wt2, 2048, 512);
  time_emb_kernel<<<dim3(16, 2), 256, 0, stream>>>(emb, W_emb, b_emb, tvec);
  bias_mask_kernel<<<dim3(16, 4), 256, 0, stream>>>(btab, tbl);

  if (big) {
    char* regionA = alloc(sz_xw);       // xw -> later x1b (bf16, 65536x512)
    char* regionQ = alloc(sz_qkv);      // qkv -> later h_c (134 MB) + ln2b (67 MB)
    bf16* attnO   = (bf16*)alloc(sz_attnO);
    bf16* xw   = (bf16*)regionA;
    bf16* x1b  = (bf16*)regionA;
    bf16* qkv  = (bf16*)regionQ;
    bf16* h_c  = (bf16*)regionQ;
    bf16* ln2b = (bf16*)(regionQ + (size_t)32768 * 2048 * 2);

    ln1_window_kernel<<<TOTROWS / 4, 256, 0, stream>>>(x, gamma1, beta1, tvec, xw, xb);
    gemmk_kernel<0, 512><<<12 * 520, 256, 0, stream>>>(
        xw, wt_qkv, b_qkv, 1536, 12, qkv, nullptr, nullptr, 0);
    attn_mfma_kernel<<<dim3(NB * NWIN, HEADS_), 64, 0, stream>>>(qkv, attnO, tbl, 0);
    // proj: x1b = bf16(xb + C), scatter
    gemmk_kernel<2, 512><<<4 * 520, 256, 0, stream>>>(
        attnO, wt_proj, b_proj, 512, 4, x1b, nullptr, xb, 0);
    ln2_kernel<<<IMGROWS / 4, 256, 0, stream>>>(x1b, gamma2, beta2, ln2b);
    // MLP in 2 chunks of 32768 rows (h_c L3-resident between mlp1/mlp2)
    for (int mc = 0; mc < 2; ++mc) {
      long r0 = (long)mc * 32768;
      gemmk_kernel<1, 512><<<16 * 256, 256, 0, stream>>>(
          ln2b + r0 * 512, wt1, b1, 2048, 16, h_c, nullptr, nullptr, 0);
      gemmk_kernel<3, 2048><<<4 * 256, 256, 0, stream>>>(
          h_c, wt2, b2, 512, 4, nullptr, out + r0 * 512, x1b + r0 * 512, 0);
    }
  } else {
    // chunked fallback
    char* regionA = alloc(sz_xw);                     // xw -> x1b
    bf16* xw   = (bf16*)regionA;
    bf16* x1b  = (bf16*)regionA;
    bf16* qkv_c = (bf16*)alloc((size_t)ATT_CHUNK_ROWS * 1536 * 2);
    char* regionB = alloc(sz_attnO);                  // attnO -> ln2b
    bf16* attnO = (bf16*)regionB;
    bf16* ln2b  = (bf16*)regionB;
    bf16* h_c   = (bf16*)alloc((size_t)16384 * 2048 * 2);

    ln1_window_kernel<<<TOTROWS / 4, 256, 0, stream>>>(x, gamma1, beta1, tvec, xw, xb);
    for (int ac = 0; ac < 8; ++ac) {
      long r0 = (long)ac * ATT_CHUNK_ROWS;
      gemmk_kernel<0, 512><<<12 * 65, 256, 0, stream>>>(
          xw + r0 * 512, wt_qkv, b_qkv, 1536, 12, qkv_c, nullptr, nullptr, 0);
      attn_mfma_kernel<<<dim3(ATT_CHUNK_WB, HEADS_), 64, 0, stream>>>(
          qkv_c, attnO + r0 * 512, tbl, ac * ATT_CHUNK_WB);
    }
    gemmk_kernel<2, 512><<<4 * 520, 256, 0, stream>>>(
        attnO, wt_proj, b_proj, 512, 4, x1b, nullptr, xb, 0);
    ln2_kernel<<<IMGROWS / 4, 256, 0, stream>>>(x1b, gamma2, beta2, ln2b);
    for (int mc = 0; mc < 4; ++mc) {
      long r0 = (long)mc * 16384;
      gemmk_kernel<1, 512><<<16 * 128, 256, 0, stream>>>(
          ln2b + r0 * 512, wt1, b1, 2048, 16, h_c, nullptr, nullptr, 0);
      gemmk_kernel<3, 2048><<<4 * 128, 256, 0, stream>>>(
          h_c, wt2, b2, 512, 4, nullptr, out + r0 * 512, x1b + r0 * 512, 0);
    }
  }
}

// Round 16
// 823.087 us; speedup vs baseline: 1.0316x; 1.0316x over previous
//
#include <hip/hip_runtime.h>
#include <hip/hip_bf16.h>

typedef __hip_bfloat16 bf16;
typedef short short4_t __attribute__((ext_vector_type(4)));
typedef short short8 __attribute__((ext_vector_type(8)));
typedef float f32x4 __attribute__((ext_vector_type(4)));

// static config
#define DIMC 512
#define HEADS_ 16
#define NTOK 65        // 64 window tokens + 1 time token
#define NWIN 64
#define NB 16
#define HID 2048
#define TOTROWS 66560  // 16*64*65
#define IMGROWS 65536  // 16*4096
#define ATT_CHUNK_WB 128
#define ATT_CHUNK_ROWS (ATT_CHUNK_WB * NTOK)  // 8320

// ---------------- helpers ----------------

__device__ __forceinline__ float b2f(short s) {
  unsigned int u = ((unsigned int)(unsigned short)s) << 16;
  float f; __builtin_memcpy(&f, &u, 4); return f;
}
__device__ __forceinline__ short f2s(float f) {
  bf16 b = __float2bfloat16(f);
  short s; __builtin_memcpy(&s, &b, 2); return s;
}

// async global->LDS, 16B per lane; LDS dest is wave-uniform base + lane*16
__device__ __forceinline__ void async_lds16(const bf16* g, bf16* l) {
  __builtin_amdgcn_global_load_lds(
      (const __attribute__((address_space(1))) unsigned int*)g,
      (__attribute__((address_space(3))) unsigned int*)l,
      16, 0, 0);
}

// per-wave LN stats over 512 elems (8 per lane)
__device__ __forceinline__ void wave_stats512(const float* v, float& m, float& rstd)
{
  float s = 0.0f, ss = 0.0f;
  #pragma unroll
  for (int e = 0; e < 8; ++e) { s += v[e]; ss += v[e] * v[e]; }
  #pragma unroll
  for (int o = 1; o < 64; o <<= 1) { s += __shfl_xor(s, o); ss += __shfl_xor(ss, o); }
  m = s * (1.0f / 512.0f);
  rstd = rsqrtf(ss * (1.0f / 512.0f) - m * m + 1e-5f);
}

// 8-op tanh-form GELU via sigmoid identity; max abs err ~3e-4
__device__ __forceinline__ float gelu_t(float v) {
  float v2 = v * v;
  float a  = fmaf(0.044715f, v2, 1.0f);
  float e  = __builtin_exp2f(-2.3022042f * (v * a));   // exp(-2z)
  return v * __builtin_amdgcn_rcpf(1.0f + e);
}

// ---------------- small kernels ----------------

__global__ __launch_bounds__(256) void time_emb_kernel(
    const float* __restrict__ emb, const float* __restrict__ W_emb,
    const float* __restrict__ b_emb, float* __restrict__ t)
{
  int b = blockIdx.x;
  int c = blockIdx.y * 256 + threadIdx.x;
  __shared__ float se[512];
  for (int k = threadIdx.x; k < 512; k += 256) {
    float e = emb[b * 512 + k];
    se[k] = e / (1.0f + expf(-e));
  }
  __syncthreads();
  float acc = b_emb[c];
  for (int k = 0; k < 512; ++k) acc += se[k] * W_emb[k * 512 + c];
  t[b * 512 + c] = acc;
}

// W (Kd x Nd) f32 -> Wt (Nd x Kd) bf16
__global__ void transpose_cast_kernel(const float* __restrict__ W, bf16* __restrict__ Wt,
                                      int Kd, int Nd)
{
  __shared__ float tile[32][33];
  int n0 = blockIdx.x * 32, k0 = blockIdx.y * 32;
  for (int r = threadIdx.y; r < 32; r += 8)
    tile[r][threadIdx.x] = W[(long)(k0 + r) * Nd + n0 + threadIdx.x];
  __syncthreads();
  for (int r = threadIdx.y; r < 32; r += 8)
    Wt[(long)(n0 + r) * Kd + k0 + threadIdx.x] = __float2bfloat16(tile[threadIdx.x][r]);
}

// combined bias+mask table: tbl[h][wtype][i(query) 80][t(key) 80] f32
__global__ __launch_bounds__(256) void bias_mask_kernel(
    const float* __restrict__ btab, float* __restrict__ tbl)
{
  int h = blockIdx.x, wt = blockIdx.y;
  for (int idx = threadIdx.x; idx < 6400; idx += 256) {
    int i = idx / 80, t = idx % 80;
    float v;
    if (t >= 65) v = -1e30f;
    else if (i >= 64 || t == 64) v = 0.0f;
    else {
      int rel = (((i >> 3) - (t >> 3) + 7) * 15) + ((i & 7) - (t & 7) + 7);
      v = btab[rel * HEADS_ + h];
      int rci = (wt & 2) ? (((i >> 3) < 4) ? 1 : 2) : 0;
      int cci = (wt & 1) ? (((i & 7) < 4) ? 1 : 2) : 0;
      int rct = (wt & 2) ? (((t >> 3) < 4) ? 1 : 2) : 0;
      int cct = (wt & 1) ? (((t & 7) < 4) ? 1 : 2) : 0;
      if (rci * 3 + cci != rct * 3 + cct) v -= 100.0f;
    }
    tbl[(h * 4 + wt) * 6400 + idx] = v;
  }
}

// LN1 + cyclic shift + window partition + time-token append -> xw bf16 (66560 x 512)
__global__ __launch_bounds__(256) void ln1_window_kernel(
    const float* __restrict__ x, const float* __restrict__ gamma,
    const float* __restrict__ beta, const float* __restrict__ t,
    bf16* __restrict__ xw)
{
  long r = (long)blockIdx.x * 4 + (threadIdx.x >> 6);   // 0..66559
  int lane = threadIdx.x & 63;
  int wb = (int)(r / NTOK), i = (int)(r % NTOK);
  int b = wb >> 6, w = wb & 63;
  bf16* out = xw + r * 512 + lane * 8;
  if (i == 64) {
    const float* tr = t + b * 512 + lane * 8;
    short8 o;
    #pragma unroll
    for (int e = 0; e < 8; ++e) o[e] = f2s(tr[e]);
    *(short8*)out = o;
    return;
  }
  int wh = w >> 3, ww = w & 7, ih = i >> 3, iw = i & 7;
  int hsrc = ((wh * 8 + ih) + 4) & 63;
  int wsrc = ((ww * 8 + iw) + 4) & 63;
  const float* xr = x + ((long)b * 4096 + hsrc * 64 + wsrc) * 512 + lane * 8;
  float v[8];
  *(f32x4*)&v[0] = *(const f32x4*)xr;
  *(f32x4*)&v[4] = *(const f32x4*)(xr + 4);
  float m, rstd;
  wave_stats512(v, m, rstd);
  const float* g = gamma + lane * 8;
  const float* bt = beta + lane * 8;
  short8 o;
  #pragma unroll
  for (int e = 0; e < 8; ++e) o[e] = f2s((v[e] - m) * rstd * g[e] + bt[e]);
  *(short8*)out = o;
}

// LN2 over x1b rows (bf16 in, bf16 out); one WAVE per row
__global__ __launch_bounds__(256) void ln2_kernel(
    const bf16* __restrict__ x1, const float* __restrict__ gamma,
    const float* __restrict__ beta, bf16* __restrict__ out)
{
  long r = (long)blockIdx.x * 4 + (threadIdx.x >> 6);
  int lane = threadIdx.x & 63;
  short8 xv = *(const short8*)(x1 + r * 512 + lane * 8);
  float v[8];
  #pragma unroll
  for (int e = 0; e < 8; ++e) v[e] = b2f(xv[e]);
  float m, rstd;
  wave_stats512(v, m, rstd);
  const float* g = gamma + lane * 8;
  const float* bt = beta + lane * 8;
  short8 o;
  #pragma unroll
  for (int e = 0; e < 8; ++e) o[e] = f2s((v[e] - m) * rstd * g[e] + bt[e]);
  *(short8*)(out + r * 512 + lane * 8) = o;
}

// ---------------- 128x128 MFMA GEMM, BK=32, 3-buffer counted-vmcnt, 3 blk/CU --
// 256 threads = 4 waves (2M x 2N), each computing 64x64 (acc 64 VGPR).
// LDS 48 KiB single array: lA = ldsbuf (3x8KB), lB = ldsbuf+12288 (3x8KB).
// Depth-2 prefetch, vmcnt(4) counted wait, vmcnt(0) on last tile; triplet-
// peeled compile-time buffers.
// EPI 0: bf16 store (qkv) | 1: gelu->bf16 (mlp1 h)
// EPI 2: proj: x1b[scatter] = bf16(x + C)  (reads f32 x, writes bf16 x1b)
// EPI 3: mlp2: out = float(x1b) + C        (reads bf16 x1b, writes f32 out)
template<int EPI, int K>
__global__ __launch_bounds__(256, 3) void gemmk_kernel(
    const bf16* __restrict__ A, const bf16* __restrict__ Bt,
    const float* __restrict__ bias, int N, int nx,
    bf16* __restrict__ outB, float* __restrict__ outF,
    const float* __restrict__ xinF, const bf16* __restrict__ xinB, int rowOffset)
{
  constexpr int NKT = K / 32;
  static_assert((NKT - 1) % 3 == 0, "triplet peel needs NKT = 3m+1");
  __shared__ bf16 ldsbuf[6 * 128 * 32];          // lA: 3 bufs, lB: 3 bufs
  bf16* const lAp = ldsbuf;
  bf16* const lBp = ldsbuf + 3 * 4096;
  const int tid = threadIdx.x;
  const int lane = tid & 63, wv = tid >> 6;  // 4 waves
  const int wm = wv >> 1, wn = wv & 1;       // 2 x 2
  const int fr = lane & 15, fg = lane >> 4;

  // bijective XCD swizzle (m204)
  const int nwg = gridDim.x, bid = blockIdx.x;
  const int q8 = nwg >> 3, rr8 = nwg & 7;
  const int xcd = bid & 7, idx = bid >> 3;
  const int sid = (xcd < rr8 ? xcd * (q8 + 1) : rr8 * (q8 + 1) + (xcd - rr8) * q8) + idx;
  const long row0 = (long)(sid / nx) * 128;
  const long col0 = (long)(sid % nx) * 128;

  // staging: one 16B slot per lane; one wave-instr covers 16 rows (64B rows)
  const int rl = lane >> 2, sp = lane & 3;
  const int s = sp ^ ((rl >> 1) & 3);        // pre-swizzled global slot
  const bf16* ga0 = A  + (row0 + wv * 32 + rl) * (long)K + s * 8;
  const bf16* ga1 = ga0 + 16 * (long)K;
  const bf16* gb0 = Bt + (col0 + wv * 32 + rl) * (long)K + s * 8;
  const bf16* gb1 = gb0 + 16 * (long)K;

  f32x4 acc[4][4] = {};
  const int swr = (fg ^ ((fr >> 1) & 3)) << 4;   // read-side swizzled slot byte

  auto stage = [&](int buf, int t) {
    const long o = (long)t * 32;
    async_lds16(ga0 + o, &lAp[buf * 4096 + (wv * 32) * 32]);
    async_lds16(ga1 + o, &lAp[buf * 4096 + (wv * 32 + 16) * 32]);
    async_lds16(gb0 + o, &lBp[buf * 4096 + (wv * 32) * 32]);
    async_lds16(gb1 + o, &lBp[buf * 4096 + (wv * 32 + 16) * 32]);
  };

  stage(0, 0);
  stage(1, 1);

#define GBODY(BUF)                                                              \
  do {                                                                          \
    if (t + 1 < NKT) asm volatile("s_waitcnt vmcnt(4)" ::: "memory");           \
    else             asm volatile("s_waitcnt vmcnt(0)" ::: "memory");           \
    __builtin_amdgcn_s_barrier();                                               \
    short8 bfv[4], af[4];                                                       \
    _Pragma("unroll")                                                           \
    for (int ni = 0; ni < 4; ++ni)                                              \
      bfv[ni] = *(const short8*)((const char*)&lBp[(BUF) * 4096] +              \
                                 (wn * 64 + ni * 16 + fr) * 64 + swr);          \
    _Pragma("unroll")                                                           \
    for (int mi = 0; mi < 4; ++mi)                                              \
      af[mi] = *(const short8*)((const char*)&lAp[(BUF) * 4096] +               \
                                (wm * 64 + mi * 16 + fr) * 64 + swr);           \
    if (t + 2 < NKT) stage(((BUF) + 2) % 3, t + 2);                             \
    __builtin_amdgcn_s_setprio(1);                                              \
    _Pragma("unroll")                                                           \
    for (int mi = 0; mi < 4; ++mi)                                              \
      _Pragma("unroll")                                                         \
      for (int ni = 0; ni < 4; ++ni)                                            \
        acc[mi][ni] = __builtin_amdgcn_mfma_f32_16x16x32_bf16(                  \
            af[mi], bfv[ni], acc[mi][ni], 0, 0, 0);                             \
    __builtin_amdgcn_s_setprio(0);                                              \
    ++t;                                                                        \
  } while (0)

  int t = 0;
  GBODY(0);                                     // t = 0 (buf 0)
  for (int g = 0; g < (NKT - 1) / 3; ++g) {     // triplets with fixed bufs
    GBODY(1);
    GBODY(2);
    GBODY(0);
  }
#undef GBODY

  if (EPI == 2 || EPI == 3) {
    // LDS-transposed epilogue: frag->LDS (64x132 f32, pad), then row-major
    // vectorized global I/O (half-wave per row).
    __syncthreads();                       // all frag reads done; LDS reusable
    float* ep = (float*)ldsbuf;            // 64*132*4 = 33.8 KB (< 48 KB)
    const int l31 = lane & 31, lr2 = lane >> 5;
    const f32x4 b4 = *(const f32x4*)&bias[col0 + l31 * 4];
    #pragma unroll
    for (int h = 0; h < 2; ++h) {
      if (wm == h) {
        #pragma unroll
        for (int mi = 0; mi < 4; ++mi)
          #pragma unroll
          for (int ni = 0; ni < 4; ++ni)
            #pragma unroll
            for (int j = 0; j < 4; ++j)
              ep[(mi * 16 + fg * 4 + j) * 132 + wn * 64 + ni * 16 + fr] = acc[mi][ni][j];
      }
      __syncthreads();
      #pragma unroll
      for (int it = 0; it < 8; ++it) {
        int lrow = it * 8 + wv * 2 + lr2;
        long rr = row0 + h * 64 + lrow;
        f32x4 v = *(const f32x4*)&ep[lrow * 132 + l31 * 4];
        v += b4;
        if (EPI == 2) {
          int grow = rowOffset + (int)rr;
          int ii = grow % NTOK;
          if (ii != 64) {
            int wb = grow / NTOK;
            int b = wb >> 6, w = wb & 63;
            int wh = w >> 3, ww = w & 7, ih = ii >> 3, iw = ii & 7;
            int hh   = ((wh * 8 + ih) + 4) & 63;
            int wcol = ((ww * 8 + iw) + 4) & 63;
            long o = ((long)b * 4096 + hh * 64 + wcol) * 512 + col0 + l31 * 4;
            f32x4 xi = *(const f32x4*)&xinF[o];
            f32x4 x1 = xi + v;
            short4_t s4;
            #pragma unroll
            for (int e = 0; e < 4; ++e) s4[e] = f2s(x1[e]);
            *(short4_t*)&outB[o] = s4;     // x1b (bf16)
          }
        } else {
          long o = rr * N + col0 + l31 * 4;
          short4_t xv = *(const short4_t*)&xinB[o];
          f32x4 xf;
          #pragma unroll
          for (int e = 0; e < 4; ++e) xf[e] = b2f(xv[e]);
          *(f32x4*)&outF[o] = xf + v;      // final out (f32)
        }
      }
      __syncthreads();
    }
    return;
  }

  // direct epilogue (bf16 outputs)
  float bs[4];
  #pragma unroll
  for (int ni = 0; ni < 4; ++ni) bs[ni] = bias[col0 + wn * 64 + ni * 16 + fr];
  #pragma unroll
  for (int mi = 0; mi < 4; ++mi) {
    #pragma unroll
    for (int j = 0; j < 4; ++j) {
      long rr = row0 + wm * 64 + mi * 16 + fg * 4 + j;
      #pragma unroll
      for (int ni = 0; ni < 4; ++ni) {
        long cc = col0 + wn * 64 + ni * 16 + fr;
        float v = acc[mi][ni][j] + bs[ni];
        if (EPI == 0) {
          outB[rr * N + cc] = __float2bfloat16(v);
        } else {
          outB[rr * N + cc] = __float2bfloat16(gelu_t(v));
        }
      }
    }
  }
}

// ---------------- MFMA windowed attention: one wave per (window-batch, head) ----
__global__ __launch_bounds__(64, 2) void attn_mfma_kernel(
    const bf16* __restrict__ qkv, bf16* __restrict__ attnO,
    const float* __restrict__ tbl, int wb0)
{
  __shared__ bf16 P[80 * 104];
  const int lwb = blockIdx.x, h = blockIdx.y;
  const int lane = threadIdx.x;
  const int fr = lane & 15, g = lane >> 4;
  const float scale = 0.17677669529663687f;   // 1/sqrt(32)
  const bf16* base = qkv + (long)lwb * 65 * 1536 + h * 32 + g * 8;

  // zero P pad slots (t in [80,104))
  for (int idx = lane; idx < 240; idx += 64) {
    int i = idx / 3, sl = idx % 3;
    *(short8*)&P[i * 104 + 80 + sl * 8] = (short8){0, 0, 0, 0, 0, 0, 0, 0};
  }

  short8 bq[5];
  #pragma unroll
  for (int tn = 0; tn < 5; ++tn) {
    int qr = tn * 16 + fr; qr = qr > 64 ? 64 : qr;
    bq[tn] = *(const short8*)(base + (long)qr * 1536);
  }

  f32x4 acc[5][5];
  #pragma unroll
  for (int tm = 0; tm < 5; ++tm) {
    int kr = tm * 16 + fr; kr = kr > 64 ? 64 : kr;
    short8 ak = *(const short8*)(base + 512 + (long)kr * 1536);
    #pragma unroll
    for (int tn = 0; tn < 5; ++tn)
      acc[tm][tn] = __builtin_amdgcn_mfma_f32_16x16x32_bf16(
          ak, bq[tn], (f32x4){0.0f, 0.0f, 0.0f, 0.0f}, 0, 0, 0);
  }

  const int w = (wb0 + lwb) & 63;
  const int wt = (((w >> 3) == 7) ? 2 : 0) + (((w & 7) == 7) ? 1 : 0);
  const float* tp = tbl + (h * 4 + wt) * 6400;
  #pragma unroll
  for (int tn = 0; tn < 5; ++tn) {
    const int i = tn * 16 + fr;
    const float* ti = tp + i * 80 + g * 4;
    float m = -3.0e38f;
    #pragma unroll
    for (int tm = 0; tm < 5; ++tm) {
      f32x4 bv = *(const f32x4*)(ti + tm * 16);
      #pragma unroll
      for (int r = 0; r < 4; ++r) {
        float sv = fmaf(acc[tm][tn][r], scale, bv[r]);
        acc[tm][tn][r] = sv;
        m = fmaxf(m, sv);
      }
    }
    m = fmaxf(m, __shfl_xor(m, 16));
    m = fmaxf(m, __shfl_xor(m, 32));
    float l = 0.0f;
    #pragma unroll
    for (int tm = 0; tm < 5; ++tm)
      #pragma unroll
      for (int r = 0; r < 4; ++r) {
        float e = __expf(acc[tm][tn][r] - m);
        acc[tm][tn][r] = e;
        l += e;
      }
    l += __shfl_xor(l, 16);
    l += __shfl_xor(l, 32);
    float inv = 1.0f / l;
    #pragma unroll
    for (int tm = 0; tm < 5; ++tm) {
      short4_t pk;
      #pragma unroll
      for (int r = 0; r < 4; ++r) pk[r] = f2s(acc[tm][tn][r] * inv);
      *(short4_t*)&P[i * 104 + tm * 16 + g * 4] = pk;
    }
  }

  const bf16* vbase = qkv + (long)lwb * 65 * 1536 + 1024 + h * 32;
  f32x4 oacc[2][5] = {};
  #pragma unroll
  for (int kt = 0; kt < 3; ++kt) {
    short8 bp[5];
    #pragma unroll
    for (int tn = 0; tn < 5; ++tn)
      bp[tn] = *(const short8*)&P[(tn * 16 + fr) * 104 + kt * 32 + g * 8];
    #pragma unroll
    for (int ma = 0; ma < 2; ++ma) {
      short8 av;
      #pragma unroll
      for (int e = 0; e < 8; ++e) {
        int vr = kt * 32 + g * 8 + e; vr = vr > 64 ? 64 : vr;
        av[e] = *(const short*)(vbase + (long)vr * 1536 + ma * 16 + fr);
      }
      #pragma unroll
      for (int tn = 0; tn < 5; ++tn)
        oacc[ma][tn] = __builtin_amdgcn_mfma_f32_16x16x32_bf16(
            av, bp[tn], oacc[ma][tn], 0, 0, 0);
    }
  }

  #pragma unroll
  for (int tn = 0; tn < 5; ++tn) {
    int i = tn * 16 + fr;
    if (i < 65) {
      bf16* op = attnO + (long)(lwb * 65 + i) * 512 + h * 32 + g * 4;
      #pragma unroll
      for (int ma = 0; ma < 2; ++ma) {
        short4_t o4;
        #pragma unroll
        for (int r = 0; r < 4; ++r) o4[r] = f2s(oacc[ma][tn][r]);
        *(short4_t*)(op + ma * 16) = o4;
      }
    }
  }
}

// ---------------- host ----------------

extern "C" void kernel_launch(void* const* d_in, const int* in_sizes, int n_in,
                              void* d_out, int out_size, void* d_ws, size_t ws_size,
                              hipStream_t stream)
{
  const float* x      = (const float*)d_in[0];
  const float* emb    = (const float*)d_in[1];
  const float* gamma1 = (const float*)d_in[2];
  const float* beta1  = (const float*)d_in[3];
  const float* W_emb  = (const float*)d_in[4];
  const float* b_emb  = (const float*)d_in[5];
  const float* W_qkv  = (const float*)d_in[6];
  const float* b_qkv  = (const float*)d_in[7];
  const float* btab   = (const float*)d_in[8];
  const float* W_proj = (const float*)d_in[9];
  const float* b_proj = (const float*)d_in[10];
  const float* gamma2 = (const float*)d_in[11];
  const float* beta2  = (const float*)d_in[12];
  const float* W1     = (const float*)d_in[13];
  const float* b1     = (const float*)d_in[14];
  const float* W2     = (const float*)d_in[15];
  const float* b2     = (const float*)d_in[16];
  float* out = (float*)d_out;
  (void)n_in; (void)in_sizes; (void)out_size;

  char* ws = (char*)d_ws;
  size_t off = 0;
  auto alloc = [&](size_t bytes) -> char* {
    char* p = ws + off;
    off += (bytes + 255) & ~(size_t)255;
    return p;
  };
  bf16* wt_qkv  = (bf16*)alloc((size_t)1536 * 512 * 2);
  bf16* wt_proj = (bf16*)alloc((size_t)512 * 512 * 2);
  bf16* wt1     = (bf16*)alloc((size_t)2048 * 512 * 2);
  bf16* wt2     = (bf16*)alloc((size_t)512 * 2048 * 2);
  float* tvec   = (float*)alloc((size_t)16 * 512 * 4);
  float* tbl    = (float*)alloc((size_t)16 * 4 * 6400 * 4);

  const size_t sz_xw    = (size_t)TOTROWS * 512 * 2;
  const size_t sz_qkv   = (size_t)TOTROWS * 1536 * 2;   // 204 MB
  const size_t sz_attnO = (size_t)TOTROWS * 512 * 2;
  const bool big = ws_size >= off + sz_xw + sz_qkv + sz_attnO + (4u << 20);

  // weight prep (common)
  transpose_cast_kernel<<<dim3(1536 / 32, 512 / 32), dim3(32, 8), 0, stream>>>(W_qkv, wt_qkv, 512, 1536);
  transpose_cast_kernel<<<dim3(512 / 32, 512 / 32),  dim3(32, 8), 0, stream>>>(W_proj, wt_proj, 512, 512);
  transpose_cast_kernel<<<dim3(2048 / 32, 512 / 32), dim3(32, 8), 0, stream>>>(W1, wt1, 512, 2048);
  transpose_cast_kernel<<<dim3(512 / 32, 2048 / 32), dim3(32, 8), 0, stream>>>(W2, wt2, 2048, 512);
  time_emb_kernel<<<dim3(16, 2), 256, 0, stream>>>(emb, W_emb, b_emb, tvec);
  bias_mask_kernel<<<dim3(16, 4), 256, 0, stream>>>(btab, tbl);

  if (big) {
    char* regionA = alloc(sz_xw);       // xw -> later x1b (bf16, 65536x512)
    char* regionQ = alloc(sz_qkv);      // qkv -> later h_c (134 MB) + ln2b (67 MB)
    bf16* attnO   = (bf16*)alloc(sz_attnO);
    bf16* xw   = (bf16*)regionA;
    bf16* x1b  = (bf16*)regionA;
    bf16* qkv  = (bf16*)regionQ;
    bf16* h_c  = (bf16*)regionQ;
    bf16* ln2b = (bf16*)(regionQ + (size_t)32768 * 2048 * 2);

    ln1_window_kernel<<<TOTROWS / 4, 256, 0, stream>>>(x, gamma1, beta1, tvec, xw);
    // qkv: M=66560, N=1536, K=512 -> 520 x 12
    gemmk_kernel<0, 512><<<12 * 520, 256, 0, stream>>>(
        xw, wt_qkv, b_qkv, 1536, 12, qkv, nullptr, nullptr, nullptr, 0);
    attn_mfma_kernel<<<dim3(NB * NWIN, HEADS_), 64, 0, stream>>>(qkv, attnO, tbl, 0);
    // proj: M=66560, N=512, K=512 -> x1b = bf16(x + C), scatter
    gemmk_kernel<2, 512><<<4 * 520, 256, 0, stream>>>(
        attnO, wt_proj, b_proj, 512, 4, x1b, nullptr, x, nullptr, 0);
    // LN2 on x1b
    ln2_kernel<<<IMGROWS / 4, 256, 0, stream>>>(x1b, gamma2, beta2, ln2b);
    // MLP in 2 chunks of 32768 rows (h_c stays L3-resident between mlp1/mlp2)
    for (int mc = 0; mc < 2; ++mc) {
      long r0 = (long)mc * 32768;
      gemmk_kernel<1, 512><<<16 * 256, 256, 0, stream>>>(
          ln2b + r0 * 512, wt1, b1, 2048, 16, h_c, nullptr, nullptr, nullptr, 0);
      gemmk_kernel<3, 2048><<<4 * 256, 256, 0, stream>>>(
          h_c, wt2, b2, 512, 4, nullptr, out + r0 * 512, nullptr, x1b + r0 * 512, 0);
    }
  } else {
    // chunked fallback
    char* regionA = alloc(sz_xw);                     // xw -> x1b
    bf16* xw   = (bf16*)regionA;
    bf16* x1b  = (bf16*)regionA;
    bf16* qkv_c = (bf16*)alloc((size_t)ATT_CHUNK_ROWS * 1536 * 2);
    char* regionB = alloc(sz_attnO);                  // attnO -> ln2b
    bf16* attnO = (bf16*)regionB;
    bf16* ln2b  = (bf16*)regionB;
    bf16* h_c   = (bf16*)alloc((size_t)16384 * 2048 * 2);

    ln1_window_kernel<<<TOTROWS / 4, 256, 0, stream>>>(x, gamma1, beta1, tvec, xw);
    for (int ac = 0; ac < 8; ++ac) {
      long r0 = (long)ac * ATT_CHUNK_ROWS;
      gemmk_kernel<0, 512><<<12 * 65, 256, 0, stream>>>(
          xw + r0 * 512, wt_qkv, b_qkv, 1536, 12, qkv_c, nullptr, nullptr, nullptr, 0);
      attn_mfma_kernel<<<dim3(ATT_CHUNK_WB, HEADS_), 64, 0, stream>>>(
          qkv_c, attnO + r0 * 512, tbl, ac * ATT_CHUNK_WB);
    }
    gemmk_kernel<2, 512><<<4 * 520, 256, 0, stream>>>(
        attnO, wt_proj, b_proj, 512, 4, x1b, nullptr, x, nullptr, 0);
    ln2_kernel<<<IMGROWS / 4, 256, 0, stream>>>(x1b, gamma2, beta2, ln2b);
    for (int mc = 0; mc < 4; ++mc) {
      long r0 = (long)mc * 16384;
      gemmk_kernel<1, 512><<<16 * 128, 256, 0, stream>>>(
          ln2b + r0 * 512, wt1, b1, 2048, 16, h_c, nullptr, nullptr, nullptr, 0);
      gemmk_kernel<3, 2048><<<4 * 128, 256, 0, stream>>>(
          h_c, wt2, b2, 512, 4, nullptr, out + r0 * 512, nullptr, x1b + r0 * 512, 0);
    }
  }
}

// Round 17
// 781.984 us; speedup vs baseline: 1.0858x; 1.0526x over previous
//
#include <hip/hip_runtime.h>
#include <hip/hip_bf16.h>

typedef __hip_bfloat16 bf16;
typedef short short4_t __attribute__((ext_vector_type(4)));
typedef short short8 __attribute__((ext_vector_type(8)));
typedef float f32x4 __attribute__((ext_vector_type(4)));

// static config
#define DIMC 512
#define HEADS_ 16
#define NTOK 65        // 64 window tokens + 1 time token
#define NWIN 64
#define NB 16
#define HID 2048
#define TOTROWS 66560  // 16*64*65
#define IMGROWS 65536  // 16*4096
#define ATT_CHUNK_WB 128
#define ATT_CHUNK_ROWS (ATT_CHUNK_WB * NTOK)  // 8320

// ---------------- helpers ----------------

__device__ __forceinline__ float b2f(short s) {
  unsigned int u = ((unsigned int)(unsigned short)s) << 16;
  float f; __builtin_memcpy(&f, &u, 4); return f;
}
__device__ __forceinline__ short f2s(float f) {
  bf16 b = __float2bfloat16(f);
  short s; __builtin_memcpy(&s, &b, 2); return s;
}

// async global->LDS, 16B per lane; LDS dest is wave-uniform base + lane*16
__device__ __forceinline__ void async_lds16(const bf16* g, bf16* l) {
  __builtin_amdgcn_global_load_lds(
      (const __attribute__((address_space(1))) unsigned int*)g,
      (__attribute__((address_space(3))) unsigned int*)l,
      16, 0, 0);
}

// per-wave LN stats over 512 elems (8 per lane)
__device__ __forceinline__ void wave_stats512(const float* v, float& m, float& rstd)
{
  float s = 0.0f, ss = 0.0f;
  #pragma unroll
  for (int e = 0; e < 8; ++e) { s += v[e]; ss += v[e] * v[e]; }
  #pragma unroll
  for (int o = 1; o < 64; o <<= 1) { s += __shfl_xor(s, o); ss += __shfl_xor(ss, o); }
  m = s * (1.0f / 512.0f);
  rstd = rsqrtf(ss * (1.0f / 512.0f) - m * m + 1e-5f);
}

// 8-op tanh-form GELU via sigmoid identity; max abs err ~3e-4
__device__ __forceinline__ float gelu_t(float v) {
  float v2 = v * v;
  float a  = fmaf(0.044715f, v2, 1.0f);
  float e  = __builtin_exp2f(-2.3022042f * (v * a));   // exp(-2z)
  return v * __builtin_amdgcn_rcpf(1.0f + e);
}

// ---------------- small kernels ----------------

__global__ __launch_bounds__(256) void time_emb_kernel(
    const float* __restrict__ emb, const float* __restrict__ W_emb,
    const float* __restrict__ b_emb, float* __restrict__ t)
{
  int b = blockIdx.x;
  int c = blockIdx.y * 256 + threadIdx.x;
  __shared__ float se[512];
  for (int k = threadIdx.x; k < 512; k += 256) {
    float e = emb[b * 512 + k];
    se[k] = e / (1.0f + expf(-e));
  }
  __syncthreads();
  float acc = b_emb[c];
  for (int k = 0; k < 512; ++k) acc += se[k] * W_emb[k * 512 + c];
  t[b * 512 + c] = acc;
}

// W (Kd x Nd) f32 -> Wt (Nd x Kd) bf16
__global__ void transpose_cast_kernel(const float* __restrict__ W, bf16* __restrict__ Wt,
                                      int Kd, int Nd)
{
  __shared__ float tile[32][33];
  int n0 = blockIdx.x * 32, k0 = blockIdx.y * 32;
  for (int r = threadIdx.y; r < 32; r += 8)
    tile[r][threadIdx.x] = W[(long)(k0 + r) * Nd + n0 + threadIdx.x];
  __syncthreads();
  for (int r = threadIdx.y; r < 32; r += 8)
    Wt[(long)(n0 + r) * Kd + k0 + threadIdx.x] = __float2bfloat16(tile[threadIdx.x][r]);
}

// combined bias+mask table: tbl[h][wtype][i(query) 80][t(key) 80] f32
__global__ __launch_bounds__(256) void bias_mask_kernel(
    const float* __restrict__ btab, float* __restrict__ tbl)
{
  int h = blockIdx.x, wt = blockIdx.y;
  for (int idx = threadIdx.x; idx < 6400; idx += 256) {
    int i = idx / 80, t = idx % 80;
    float v;
    if (t >= 65) v = -1e30f;
    else if (i >= 64 || t == 64) v = 0.0f;
    else {
      int rel = (((i >> 3) - (t >> 3) + 7) * 15) + ((i & 7) - (t & 7) + 7);
      v = btab[rel * HEADS_ + h];
      int rci = (wt & 2) ? (((i >> 3) < 4) ? 1 : 2) : 0;
      int cci = (wt & 1) ? (((i & 7) < 4) ? 1 : 2) : 0;
      int rct = (wt & 2) ? (((t >> 3) < 4) ? 1 : 2) : 0;
      int cct = (wt & 1) ? (((t & 7) < 4) ? 1 : 2) : 0;
      if (rci * 3 + cci != rct * 3 + cct) v -= 100.0f;
    }
    tbl[(h * 4 + wt) * 6400 + idx] = v;
  }
}

// LN1 + cyclic shift + window partition + time-token append -> xw bf16 (66560 x 512)
__global__ __launch_bounds__(256) void ln1_window_kernel(
    const float* __restrict__ x, const float* __restrict__ gamma,
    const float* __restrict__ beta, const float* __restrict__ t,
    bf16* __restrict__ xw)
{
  long r = (long)blockIdx.x * 4 + (threadIdx.x >> 6);   // 0..66559
  int lane = threadIdx.x & 63;
  int wb = (int)(r / NTOK), i = (int)(r % NTOK);
  int b = wb >> 6, w = wb & 63;
  bf16* out = xw + r * 512 + lane * 8;
  if (i == 64) {
    const float* tr = t + b * 512 + lane * 8;
    short8 o;
    #pragma unroll
    for (int e = 0; e < 8; ++e) o[e] = f2s(tr[e]);
    *(short8*)out = o;
    return;
  }
  int wh = w >> 3, ww = w & 7, ih = i >> 3, iw = i & 7;
  int hsrc = ((wh * 8 + ih) + 4) & 63;
  int wsrc = ((ww * 8 + iw) + 4) & 63;
  const float* xr = x + ((long)b * 4096 + hsrc * 64 + wsrc) * 512 + lane * 8;
  float v[8];
  *(f32x4*)&v[0] = *(const f32x4*)xr;
  *(f32x4*)&v[4] = *(const f32x4*)(xr + 4);
  float m, rstd;
  wave_stats512(v, m, rstd);
  const float* g = gamma + lane * 8;
  const float* bt = beta + lane * 8;
  short8 o;
  #pragma unroll
  for (int e = 0; e < 8; ++e) o[e] = f2s((v[e] - m) * rstd * g[e] + bt[e]);
  *(short8*)out = o;
}

// LN2 over x1b rows (bf16 in, bf16 out); one WAVE per row
__global__ __launch_bounds__(256) void ln2_kernel(
    const bf16* __restrict__ x1, const float* __restrict__ gamma,
    const float* __restrict__ beta, bf16* __restrict__ out)
{
  long r = (long)blockIdx.x * 4 + (threadIdx.x >> 6);
  int lane = threadIdx.x & 63;
  short8 xv = *(const short8*)(x1 + r * 512 + lane * 8);
  float v[8];
  #pragma unroll
  for (int e = 0; e < 8; ++e) v[e] = b2f(xv[e]);
  float m, rstd;
  wave_stats512(v, m, rstd);
  const float* g = gamma + lane * 8;
  const float* bt = beta + lane * 8;
  short8 o;
  #pragma unroll
  for (int e = 0; e < 8; ++e) o[e] = f2s((v[e] - m) * rstd * g[e] + bt[e]);
  *(short8*)(out + r * 512 + lane * 8) = o;
}

// ---------------- 256x256 8-wave 4-phase MFMA GEMM, half-tile counted vmcnt --
// 512 threads = 8 waves (2M x 4N); per-wave output 128x64: rows wm*64+[0,64)
// in BOTH halves, cols wn*32+[0,32) in both B-halves. Phases = C-quadrants
// (mh,nh) in order (0,0),(0,1),(1,0),(1,1): 16 MFMA each; A-frags held across
// nh pair. LDS 128 KiB: lds[buf*4 + mat*2 + half][128*64], XOR-8 swizzled.
// Staging: during tile t, tile t+1's half-tiles issued [Ah0@p0, Bh0@p1,
// Bh1@p2, Ah1@p3] (2 loads/thread each) -> steady waits vmcnt(4) at p0/p1/p2,
// never 0; tail tile waits (4,2,0). EPI 0: bf16 | 1: gelu->bf16 |
// 2: proj x1b=bf16(x+C) scatter | 3: mlp2 out=float(x1b)+C (both via LDS ep).
template<int EPI, int K>
__global__ __launch_bounds__(512, 1) void gemm8p_kernel(
    const bf16* __restrict__ A, const bf16* __restrict__ Bt,
    const float* __restrict__ bias, int N, int nx,
    bf16* __restrict__ outB, float* __restrict__ outF,
    const float* __restrict__ xinF, const bf16* __restrict__ xinB, int rowOffset)
{
  constexpr int NKT = K / 64;
  __shared__ bf16 lds[8][128 * 64];    // [buf*4 + mat*2 + half]
  const int tid = threadIdx.x;
  const int lane = tid & 63, wv = tid >> 6;
  const int wm = wv >> 2, wn = wv & 3;
  const int fr = lane & 15, fg = lane >> 4;

  // bijective XCD swizzle (m204)
  const int nwg = gridDim.x, bid = blockIdx.x;
  const int q8 = nwg >> 3, rr8 = nwg & 7;
  const int xcd = bid & 7, idx = bid >> 3;
  const int sid = (xcd < rr8 ? xcd * (q8 + 1) : rr8 * (q8 + 1) + (xcd - rr8) * q8) + idx;
  const long row0 = (long)(sid / nx) * 256;
  const long col0 = (long)(sid % nx) * 256;

  const int rl = lane >> 3, sl = lane & 7;
  const int sls = sl ^ rl;                    // pre-swizzled global slot

  auto stageH = [&](int buf, int mat, int h, int kt) {
    const bf16* base = mat ? Bt : A;
    const long rb = (mat ? col0 : row0) + h * 128 + wv * 8 + rl;
    const bf16* src = base + rb * (long)K + kt + sls * 8;
    bf16* dst = &lds[buf * 4 + mat * 2 + h][(wv * 8) * 64];
    async_lds16(src, dst);
    async_lds16(src + 64 * (long)K, dst + 64 * 64);
  };
  auto fragA = [&](int buf, int h, int mi, int ks) -> short8 {
    int r = wm * 64 + mi * 16 + fr;
    return *(const short8*)((const char*)&lds[buf * 4 + h][0] + r * 128 + (((ks * 4 + fg) ^ (r & 7)) << 4));
  };
  auto fragB = [&](int buf, int h, int ni, int ks) -> short8 {
    int r = wn * 32 + ni * 16 + fr;
    return *(const short8*)((const char*)&lds[buf * 4 + 2 + h][0] + r * 128 + (((ks * 4 + fg) ^ (r & 7)) << 4));
  };

  f32x4 acc[8][4] = {};                 // [h*4+mi][nh*2+ni]
  short8 af[4][2], bv[2][2];

  // prologue: tile 0 in steady stage order [Ah0, Bh0, Bh1, Ah1]
  stageH(0, 0, 0, 0); stageH(0, 1, 0, 0); stageH(0, 1, 1, 0); stageH(0, 0, 1, 0);

  for (int t = 0; t < NKT; ++t) {
    const int buf = t & 1, nb = buf ^ 1;
    const bool st = (t + 1 < NKT);
    const int kt2 = (t + 1) << 6;

    // phase 0: (mh0, nh0) — needs Ah0, Bh0 (oldest 4 loads)
    asm volatile("s_waitcnt vmcnt(4)" ::: "memory");
    __builtin_amdgcn_s_barrier();
    #pragma unroll
    for (int mi = 0; mi < 4; ++mi) { af[mi][0] = fragA(buf, 0, mi, 0); af[mi][1] = fragA(buf, 0, mi, 1); }
    #pragma unroll
    for (int ni = 0; ni < 2; ++ni) { bv[ni][0] = fragB(buf, 0, ni, 0); bv[ni][1] = fragB(buf, 0, ni, 1); }
    if (st) stageH(nb, 0, 0, kt2);            // Ah0'
    __builtin_amdgcn_s_setprio(1);
    #pragma unroll
    for (int mi = 0; mi < 4; ++mi)
      #pragma unroll
      for (int ni = 0; ni < 2; ++ni)
        #pragma unroll
        for (int ks = 0; ks < 2; ++ks)
          acc[mi][ni] = __builtin_amdgcn_mfma_f32_16x16x32_bf16(af[mi][ks], bv[ni][ks], acc[mi][ni], 0, 0, 0);
    __builtin_amdgcn_s_setprio(0);

    // phase 1: (0,1) — needs Bh1
    if (st) asm volatile("s_waitcnt vmcnt(4)" ::: "memory");
    else    asm volatile("s_waitcnt vmcnt(2)" ::: "memory");
    __builtin_amdgcn_s_barrier();
    #pragma unroll
    for (int ni = 0; ni < 2; ++ni) { bv[ni][0] = fragB(buf, 1, ni, 0); bv[ni][1] = fragB(buf, 1, ni, 1); }
    if (st) stageH(nb, 1, 0, kt2);            // Bh0'
    __builtin_amdgcn_s_setprio(1);
    #pragma unroll
    for (int mi = 0; mi < 4; ++mi)
      #pragma unroll
      for (int ni = 0; ni < 2; ++ni)
        #pragma unroll
        for (int ks = 0; ks < 2; ++ks)
          acc[mi][2 + ni] = __builtin_amdgcn_mfma_f32_16x16x32_bf16(af[mi][ks], bv[ni][ks], acc[mi][2 + ni], 0, 0, 0);
    __builtin_amdgcn_s_setprio(0);

    // phase 2: (1,0) — needs Ah1
    if (st) asm volatile("s_waitcnt vmcnt(4)" ::: "memory");
    else    asm volatile("s_waitcnt vmcnt(0)" ::: "memory");
    __builtin_amdgcn_s_barrier();
    #pragma unroll
    for (int mi = 0; mi < 4; ++mi) { af[mi][0] = fragA(buf, 1, mi, 0); af[mi][1] = fragA(buf, 1, mi, 1); }
    #pragma unroll
    for (int ni = 0; ni < 2; ++ni) { bv[ni][0] = fragB(buf, 0, ni, 0); bv[ni][1] = fragB(buf, 0, ni, 1); }
    if (st) stageH(nb, 1, 1, kt2);            // Bh1'
    __builtin_amdgcn_s_setprio(1);
    #pragma unroll
    for (int mi = 0; mi < 4; ++mi)
      #pragma unroll
      for (int ni = 0; ni < 2; ++ni)
        #pragma unroll
        for (int ks = 0; ks < 2; ++ks)
          acc[4 + mi][ni] = __builtin_amdgcn_mfma_f32_16x16x32_bf16(af[mi][ks], bv[ni][ks], acc[4 + mi][ni], 0, 0, 0);
    __builtin_amdgcn_s_setprio(0);

    // phase 3: (1,1) — everything resident
    __builtin_amdgcn_s_barrier();
    #pragma unroll
    for (int ni = 0; ni < 2; ++ni) { bv[ni][0] = fragB(buf, 1, ni, 0); bv[ni][1] = fragB(buf, 1, ni, 1); }
    if (st) stageH(nb, 0, 1, kt2);            // Ah1'
    __builtin_amdgcn_s_setprio(1);
    #pragma unroll
    for (int mi = 0; mi < 4; ++mi)
      #pragma unroll
      for (int ni = 0; ni < 2; ++ni)
        #pragma unroll
        for (int ks = 0; ks < 2; ++ks)
          acc[4 + mi][2 + ni] = __builtin_amdgcn_mfma_f32_16x16x32_bf16(af[mi][ks], bv[ni][ks], acc[4 + mi][2 + ni], 0, 0, 0);
    __builtin_amdgcn_s_setprio(0);
  }

  if (EPI == 0 || EPI == 1) {
    // direct scalar epilogue (proven fastest for bf16 outputs, r15 A/B)
    float bs[2][2];
    #pragma unroll
    for (int nh = 0; nh < 2; ++nh)
      #pragma unroll
      for (int ni = 0; ni < 2; ++ni)
        bs[nh][ni] = bias[col0 + nh * 128 + wn * 32 + ni * 16 + fr];
    #pragma unroll
    for (int h = 0; h < 2; ++h)
      #pragma unroll
      for (int mi = 0; mi < 4; ++mi)
        #pragma unroll
        for (int j = 0; j < 4; ++j) {
          long rr = row0 + h * 128 + wm * 64 + mi * 16 + fg * 4 + j;
          #pragma unroll
          for (int nh = 0; nh < 2; ++nh)
            #pragma unroll
            for (int ni = 0; ni < 2; ++ni) {
              long cc = col0 + nh * 128 + wn * 32 + ni * 16 + fr;
              float v = acc[h * 4 + mi][nh * 2 + ni][j] + bs[nh][ni];
              if (EPI == 1) v = gelu_t(v);
              outB[rr * N + cc] = __float2bfloat16(v);
            }
        }
    return;
  }

  // EPI 2/3: LDS-transposed f32 epilogue in 4 groups of 64 rows
  __syncthreads();
  float* ep = (float*)&lds[0][0];          // 64*260*4 = 66.6 KB (< 128 KB)
  const int c64 = tid & 63, r8 = tid >> 6;
  const f32x4 b4 = *(const f32x4*)&bias[col0 + c64 * 4];
  #pragma unroll
  for (int g = 0; g < 4; ++g) {
    int h = g >> 1, wmg = g & 1;
    if (wm == wmg) {
      #pragma unroll
      for (int mi = 0; mi < 4; ++mi)
        #pragma unroll
        for (int nh = 0; nh < 2; ++nh)
          #pragma unroll
          for (int ni = 0; ni < 2; ++ni)
            #pragma unroll
            for (int j = 0; j < 4; ++j)
              ep[(mi * 16 + fg * 4 + j) * 260 + nh * 128 + wn * 32 + ni * 16 + fr] =
                  acc[h * 4 + mi][nh * 2 + ni][j];
    }
    __syncthreads();
    #pragma unroll
    for (int it = 0; it < 8; ++it) {
      int lrow = it * 8 + r8;
      long rr = row0 + h * 128 + wmg * 64 + lrow;
      f32x4 v = *(const f32x4*)&ep[lrow * 260 + c64 * 4];
      v += b4;
      if (EPI == 2) {
        int grow = rowOffset + (int)rr;
        int ii = grow % NTOK;
        if (ii != 64) {
          int wb = grow / NTOK;
          int b = wb >> 6, w = wb & 63;
          int wh = w >> 3, ww = w & 7, ih = ii >> 3, iw = ii & 7;
          int hh   = ((wh * 8 + ih) + 4) & 63;
          int wcol = ((ww * 8 + iw) + 4) & 63;
          long o = ((long)b * 4096 + hh * 64 + wcol) * 512 + col0 + c64 * 4;
          f32x4 xi = *(const f32x4*)&xinF[o];
          f32x4 x1 = xi + v;
          short4_t s4;
          #pragma unroll
          for (int e = 0; e < 4; ++e) s4[e] = f2s(x1[e]);
          *(short4_t*)&outB[o] = s4;       // x1b (bf16)
        }
      } else {
        long o = rr * N + col0 + c64 * 4;
        short4_t xv = *(const short4_t*)&xinB[o];
        f32x4 xf;
        #pragma unroll
        for (int e = 0; e < 4; ++e) xf[e] = b2f(xv[e]);
        *(f32x4*)&outF[o] = xf + v;        // final out (f32)
      }
    }
    __syncthreads();
  }
}

// ---------------- 128x128 fallback GEMM (r16, proven) ----------------
template<int EPI, int K>
__global__ __launch_bounds__(256, 3) void gemmk_kernel(
    const bf16* __restrict__ A, const bf16* __restrict__ Bt,
    const float* __restrict__ bias, int N, int nx,
    bf16* __restrict__ outB, float* __restrict__ outF,
    const float* __restrict__ xinF, const bf16* __restrict__ xinB, int rowOffset)
{
  constexpr int NKT = K / 32;
  static_assert((NKT - 1) % 3 == 0, "triplet peel needs NKT = 3m+1");
  __shared__ bf16 ldsbuf[6 * 128 * 32];
  bf16* const lAp = ldsbuf;
  bf16* const lBp = ldsbuf + 3 * 4096;
  const int tid = threadIdx.x;
  const int lane = tid & 63, wv = tid >> 6;
  const int wm = wv >> 1, wn = wv & 1;
  const int fr = lane & 15, fg = lane >> 4;

  const int nwg = gridDim.x, bid = blockIdx.x;
  const int q8 = nwg >> 3, rr8 = nwg & 7;
  const int xcd = bid & 7, idx = bid >> 3;
  const int sid = (xcd < rr8 ? xcd * (q8 + 1) : rr8 * (q8 + 1) + (xcd - rr8) * q8) + idx;
  const long row0 = (long)(sid / nx) * 128;
  const long col0 = (long)(sid % nx) * 128;

  const int rl = lane >> 2, sp = lane & 3;
  const int s = sp ^ ((rl >> 1) & 3);
  const bf16* ga0 = A  + (row0 + wv * 32 + rl) * (long)K + s * 8;
  const bf16* ga1 = ga0 + 16 * (long)K;
  const bf16* gb0 = Bt + (col0 + wv * 32 + rl) * (long)K + s * 8;
  const bf16* gb1 = gb0 + 16 * (long)K;

  f32x4 acc[4][4] = {};
  const int swr = (fg ^ ((fr >> 1) & 3)) << 4;

  auto stage = [&](int buf, int t) {
    const long o = (long)t * 32;
    async_lds16(ga0 + o, &lAp[buf * 4096 + (wv * 32) * 32]);
    async_lds16(ga1 + o, &lAp[buf * 4096 + (wv * 32 + 16) * 32]);
    async_lds16(gb0 + o, &lBp[buf * 4096 + (wv * 32) * 32]);
    async_lds16(gb1 + o, &lBp[buf * 4096 + (wv * 32 + 16) * 32]);
  };

  stage(0, 0);
  stage(1, 1);

#define GBODY(BUF)                                                              \
  do {                                                                          \
    if (t + 1 < NKT) asm volatile("s_waitcnt vmcnt(4)" ::: "memory");           \
    else             asm volatile("s_waitcnt vmcnt(0)" ::: "memory");           \
    __builtin_amdgcn_s_barrier();                                               \
    short8 bfv[4], af[4];                                                       \
    _Pragma("unroll")                                                           \
    for (int ni = 0; ni < 4; ++ni)                                              \
      bfv[ni] = *(const short8*)((const char*)&lBp[(BUF) * 4096] +              \
                                 (wn * 64 + ni * 16 + fr) * 64 + swr);          \
    _Pragma("unroll")                                                           \
    for (int mi = 0; mi < 4; ++mi)                                              \
      af[mi] = *(const short8*)((const char*)&lAp[(BUF) * 4096] +               \
                                (wm * 64 + mi * 16 + fr) * 64 + swr);           \
    if (t + 2 < NKT) stage(((BUF) + 2) % 3, t + 2);                             \
    __builtin_amdgcn_s_setprio(1);                                              \
    _Pragma("unroll")                                                           \
    for (int mi = 0; mi < 4; ++mi)                                              \
      _Pragma("unroll")                                                         \
      for (int ni = 0; ni < 4; ++ni)                                            \
        acc[mi][ni] = __builtin_amdgcn_mfma_f32_16x16x32_bf16(                  \
            af[mi], bfv[ni], acc[mi][ni], 0, 0, 0);                             \
    __builtin_amdgcn_s_setprio(0);                                              \
    ++t;                                                                        \
  } while (0)

  int t = 0;
  GBODY(0);
  for (int g = 0; g < (NKT - 1) / 3; ++g) {
    GBODY(1);
    GBODY(2);
    GBODY(0);
  }
#undef GBODY

  if (EPI == 2 || EPI == 3) {
    __syncthreads();
    float* ep = (float*)ldsbuf;
    const int l31 = lane & 31, lr2 = lane >> 5;
    const f32x4 b4 = *(const f32x4*)&bias[col0 + l31 * 4];
    #pragma unroll
    for (int h = 0; h < 2; ++h) {
      if (wm == h) {
        #pragma unroll
        for (int mi = 0; mi < 4; ++mi)
          #pragma unroll
          for (int ni = 0; ni < 4; ++ni)
            #pragma unroll
            for (int j = 0; j < 4; ++j)
              ep[(mi * 16 + fg * 4 + j) * 132 + wn * 64 + ni * 16 + fr] = acc[mi][ni][j];
      }
      __syncthreads();
      #pragma unroll
      for (int it = 0; it < 8; ++it) {
        int lrow = it * 8 + wv * 2 + lr2;
        long rr = row0 + h * 64 + lrow;
        f32x4 v = *(const f32x4*)&ep[lrow * 132 + l31 * 4];
        v += b4;
        if (EPI == 2) {
          int grow = rowOffset + (int)rr;
          int ii = grow % NTOK;
          if (ii != 64) {
            int wb = grow / NTOK;
            int b = wb >> 6, w = wb & 63;
            int wh = w >> 3, ww = w & 7, ih = ii >> 3, iw = ii & 7;
            int hh   = ((wh * 8 + ih) + 4) & 63;
            int wcol = ((ww * 8 + iw) + 4) & 63;
            long o = ((long)b * 4096 + hh * 64 + wcol) * 512 + col0 + l31 * 4;
            f32x4 xi = *(const f32x4*)&xinF[o];
            f32x4 x1 = xi + v;
            short4_t s4;
            #pragma unroll
            for (int e = 0; e < 4; ++e) s4[e] = f2s(x1[e]);
            *(short4_t*)&outB[o] = s4;
          }
        } else {
          long o = rr * N + col0 + l31 * 4;
          short4_t xv = *(const short4_t*)&xinB[o];
          f32x4 xf;
          #pragma unroll
          for (int e = 0; e < 4; ++e) xf[e] = b2f(xv[e]);
          *(f32x4*)&outF[o] = xf + v;
        }
      }
      __syncthreads();
    }
    return;
  }

  float bs[4];
  #pragma unroll
  for (int ni = 0; ni < 4; ++ni) bs[ni] = bias[col0 + wn * 64 + ni * 16 + fr];
  #pragma unroll
  for (int mi = 0; mi < 4; ++mi) {
    #pragma unroll
    for (int j = 0; j < 4; ++j) {
      long rr = row0 + wm * 64 + mi * 16 + fg * 4 + j;
      #pragma unroll
      for (int ni = 0; ni < 4; ++ni) {
        long cc = col0 + wn * 64 + ni * 16 + fr;
        float v = acc[mi][ni][j] + bs[ni];
        if (EPI == 0) {
          outB[rr * N + cc] = __float2bfloat16(v);
        } else {
          outB[rr * N + cc] = __float2bfloat16(gelu_t(v));
        }
      }
    }
  }
}

// ---------------- MFMA windowed attention: one wave per (window-batch, head) ----
__global__ __launch_bounds__(64, 2) void attn_mfma_kernel(
    const bf16* __restrict__ qkv, bf16* __restrict__ attnO,
    const float* __restrict__ tbl, int wb0)
{
  __shared__ bf16 P[80 * 104];
  const int lwb = blockIdx.x, h = blockIdx.y;
  const int lane = threadIdx.x;
  const int fr = lane & 15, g = lane >> 4;
  const float scale = 0.17677669529663687f;   // 1/sqrt(32)
  const bf16* base = qkv + (long)lwb * 65 * 1536 + h * 32 + g * 8;

  for (int idx = lane; idx < 240; idx += 64) {
    int i = idx / 3, sl = idx % 3;
    *(short8*)&P[i * 104 + 80 + sl * 8] = (short8){0, 0, 0, 0, 0, 0, 0, 0};
  }

  short8 bq[5];
  #pragma unroll
  for (int tn = 0; tn < 5; ++tn) {
    int qr = tn * 16 + fr; qr = qr > 64 ? 64 : qr;
    bq[tn] = *(const short8*)(base + (long)qr * 1536);
  }

  f32x4 acc[5][5];
  #pragma unroll
  for (int tm = 0; tm < 5; ++tm) {
    int kr = tm * 16 + fr; kr = kr > 64 ? 64 : kr;
    short8 ak = *(const short8*)(base + 512 + (long)kr * 1536);
    #pragma unroll
    for (int tn = 0; tn < 5; ++tn)
      acc[tm][tn] = __builtin_amdgcn_mfma_f32_16x16x32_bf16(
          ak, bq[tn], (f32x4){0.0f, 0.0f, 0.0f, 0.0f}, 0, 0, 0);
  }

  const int w = (wb0 + lwb) & 63;
  const int wt = (((w >> 3) == 7) ? 2 : 0) + (((w & 7) == 7) ? 1 : 0);
  const float* tp = tbl + (h * 4 + wt) * 6400;
  #pragma unroll
  for (int tn = 0; tn < 5; ++tn) {
    const int i = tn * 16 + fr;
    const float* ti = tp + i * 80 + g * 4;
    float m = -3.0e38f;
    #pragma unroll
    for (int tm = 0; tm < 5; ++tm) {
      f32x4 bvv = *(const f32x4*)(ti + tm * 16);
      #pragma unroll
      for (int r = 0; r < 4; ++r) {
        float sv = fmaf(acc[tm][tn][r], scale, bvv[r]);
        acc[tm][tn][r] = sv;
        m = fmaxf(m, sv);
      }
    }
    m = fmaxf(m, __shfl_xor(m, 16));
    m = fmaxf(m, __shfl_xor(m, 32));
    float l = 0.0f;
    #pragma unroll
    for (int tm = 0; tm < 5; ++tm)
      #pragma unroll
      for (int r = 0; r < 4; ++r) {
        float e = __expf(acc[tm][tn][r] - m);
        acc[tm][tn][r] = e;
        l += e;
      }
    l += __shfl_xor(l, 16);
    l += __shfl_xor(l, 32);
    float inv = 1.0f / l;
    #pragma unroll
    for (int tm = 0; tm < 5; ++tm) {
      short4_t pk;
      #pragma unroll
      for (int r = 0; r < 4; ++r) pk[r] = f2s(acc[tm][tn][r] * inv);
      *(short4_t*)&P[i * 104 + tm * 16 + g * 4] = pk;
    }
  }

  const bf16* vbase = qkv + (long)lwb * 65 * 1536 + 1024 + h * 32;
  f32x4 oacc[2][5] = {};
  #pragma unroll
  for (int kt = 0; kt < 3; ++kt) {
    short8 bp[5];
    #pragma unroll
    for (int tn = 0; tn < 5; ++tn)
      bp[tn] = *(const short8*)&P[(tn * 16 + fr) * 104 + kt * 32 + g * 8];
    #pragma unroll
    for (int ma = 0; ma < 2; ++ma) {
      short8 av;
      #pragma unroll
      for (int e = 0; e < 8; ++e) {
        int vr = kt * 32 + g * 8 + e; vr = vr > 64 ? 64 : vr;
        av[e] = *(const short*)(vbase + (long)vr * 1536 + ma * 16 + fr);
      }
      #pragma unroll
      for (int tn = 0; tn < 5; ++tn)
        oacc[ma][tn] = __builtin_amdgcn_mfma_f32_16x16x32_bf16(
            av, bp[tn], oacc[ma][tn], 0, 0, 0);
    }
  }

  #pragma unroll
  for (int tn = 0; tn < 5; ++tn) {
    int i = tn * 16 + fr;
    if (i < 65) {
      bf16* op = attnO + (long)(lwb * 65 + i) * 512 + h * 32 + g * 4;
      #pragma unroll
      for (int ma = 0; ma < 2; ++ma) {
        short4_t o4;
        #pragma unroll
        for (int r = 0; r < 4; ++r) o4[r] = f2s(oacc[ma][tn][r]);
        *(short4_t*)(op + ma * 16) = o4;
      }
    }
  }
}

// ---------------- host ----------------

extern "C" void kernel_launch(void* const* d_in, const int* in_sizes, int n_in,
                              void* d_out, int out_size, void* d_ws, size_t ws_size,
                              hipStream_t stream)
{
  const float* x      = (const float*)d_in[0];
  const float* emb    = (const float*)d_in[1];
  const float* gamma1 = (const float*)d_in[2];
  const float* beta1  = (const float*)d_in[3];
  const float* W_emb  = (const float*)d_in[4];
  const float* b_emb  = (const float*)d_in[5];
  const float* W_qkv  = (const float*)d_in[6];
  const float* b_qkv  = (const float*)d_in[7];
  const float* btab   = (const float*)d_in[8];
  const float* W_proj = (const float*)d_in[9];
  const float* b_proj = (const float*)d_in[10];
  const float* gamma2 = (const float*)d_in[11];
  const float* beta2  = (const float*)d_in[12];
  const float* W1     = (const float*)d_in[13];
  const float* b1     = (const float*)d_in[14];
  const float* W2     = (const float*)d_in[15];
  const float* b2     = (const float*)d_in[16];
  float* out = (float*)d_out;
  (void)n_in; (void)in_sizes; (void)out_size;

  char* ws = (char*)d_ws;
  size_t off = 0;
  auto alloc = [&](size_t bytes) -> char* {
    char* p = ws + off;
    off += (bytes + 255) & ~(size_t)255;
    return p;
  };
  bf16* wt_qkv  = (bf16*)alloc((size_t)1536 * 512 * 2);
  bf16* wt_proj = (bf16*)alloc((size_t)512 * 512 * 2);
  bf16* wt1     = (bf16*)alloc((size_t)2048 * 512 * 2);
  bf16* wt2     = (bf16*)alloc((size_t)512 * 2048 * 2);
  float* tvec   = (float*)alloc((size_t)16 * 512 * 4);
  float* tbl    = (float*)alloc((size_t)16 * 4 * 6400 * 4);

  const size_t sz_xw    = (size_t)TOTROWS * 512 * 2;
  const size_t sz_qkv   = (size_t)TOTROWS * 1536 * 2;
  const size_t sz_attnO = (size_t)TOTROWS * 512 * 2;
  const bool big = ws_size >= off + sz_xw + sz_qkv + sz_attnO + (4u << 20);

  transpose_cast_kernel<<<dim3(1536 / 32, 512 / 32), dim3(32, 8), 0, stream>>>(W_qkv, wt_qkv, 512, 1536);
  transpose_cast_kernel<<<dim3(512 / 32, 512 / 32),  dim3(32, 8), 0, stream>>>(W_proj, wt_proj, 512, 512);
  transpose_cast_kernel<<<dim3(2048 / 32, 512 / 32), dim3(32, 8), 0, stream>>>(W1, wt1, 512, 2048);
  transpose_cast_kernel<<<dim3(512 / 32, 2048 / 32), dim3(32, 8), 0, stream>>>(W2, wt2, 2048, 512);
  time_emb_kernel<<<dim3(16, 2), 256, 0, stream>>>(emb, W_emb, b_emb, tvec);
  bias_mask_kernel<<<dim3(16, 4), 256, 0, stream>>>(btab, tbl);

  if (big) {
    char* regionA = alloc(sz_xw);       // xw -> later x1b
    char* regionQ = alloc(sz_qkv);      // qkv -> later h_c + ln2b
    bf16* attnO   = (bf16*)alloc(sz_attnO);
    bf16* xw   = (bf16*)regionA;
    bf16* x1b  = (bf16*)regionA;
    bf16* qkv  = (bf16*)regionQ;
    bf16* h_c  = (bf16*)regionQ;
    bf16* ln2b = (bf16*)(regionQ + (size_t)32768 * 2048 * 2);

    ln1_window_kernel<<<TOTROWS / 4, 256, 0, stream>>>(x, gamma1, beta1, tvec, xw);
    // qkv: M=66560 (260x256), N=1536 (6x256), K=512
    gemm8p_kernel<0, 512><<<6 * 260, 512, 0, stream>>>(
        xw, wt_qkv, b_qkv, 1536, 6, qkv, nullptr, nullptr, nullptr, 0);
    attn_mfma_kernel<<<dim3(NB * NWIN, HEADS_), 64, 0, stream>>>(qkv, attnO, tbl, 0);
    // proj: x1b = bf16(x + C), scatter
    gemm8p_kernel<2, 512><<<2 * 260, 512, 0, stream>>>(
        attnO, wt_proj, b_proj, 512, 2, x1b, nullptr, x, nullptr, 0);
    ln2_kernel<<<IMGROWS / 4, 256, 0, stream>>>(x1b, gamma2, beta2, ln2b);
    for (int mc = 0; mc < 2; ++mc) {
      long r0 = (long)mc * 32768;
      gemm8p_kernel<1, 512><<<8 * 128, 512, 0, stream>>>(
          ln2b + r0 * 512, wt1, b1, 2048, 8, h_c, nullptr, nullptr, nullptr, 0);
      gemm8p_kernel<3, 2048><<<2 * 128, 512, 0, stream>>>(
          h_c, wt2, b2, 512, 2, nullptr, out + r0 * 512, nullptr, x1b + r0 * 512, 0);
    }
  } else {
    // chunked fallback (proven gemmk path)
    char* regionA = alloc(sz_xw);
    bf16* xw   = (bf16*)regionA;
    bf16* x1b  = (bf16*)regionA;
    bf16* qkv_c = (bf16*)alloc((size_t)ATT_CHUNK_ROWS * 1536 * 2);
    char* regionB = alloc(sz_attnO);
    bf16* attnO = (bf16*)regionB;
    bf16* ln2b  = (bf16*)regionB;
    bf16* h_c   = (bf16*)alloc((size_t)16384 * 2048 * 2);

    ln1_window_kernel<<<TOTROWS / 4, 256, 0, stream>>>(x, gamma1, beta1, tvec, xw);
    for (int ac = 0; ac < 8; ++ac) {
      long r0 = (long)ac * ATT_CHUNK_ROWS;
      gemmk_kernel<0, 512><<<12 * 65, 256, 0, stream>>>(
          xw + r0 * 512, wt_qkv, b_qkv, 1536, 12, qkv_c, nullptr, nullptr, nullptr, 0);
      attn_mfma_kernel<<<dim3(ATT_CHUNK_WB, HEADS_), 64, 0, stream>>>(
          qkv_c, attnO + r0 * 512, tbl, ac * ATT_CHUNK_WB);
    }
    gemmk_kernel<2, 512><<<4 * 520, 256, 0, stream>>>(
        attnO, wt_proj, b_proj, 512, 4, x1b, nullptr, x, nullptr, 0);
    ln2_kernel<<<IMGROWS / 4, 256, 0, stream>>>(x1b, gamma2, beta2, ln2b);
    for (int mc = 0; mc < 4; ++mc) {
      long r0 = (long)mc * 16384;
      gemmk_kernel<1, 512><<<16 * 128, 256, 0, stream>>>(
          ln2b + r0 * 512, wt1, b1, 2048, 16, h_c, nullptr, nullptr, nullptr, 0);
      gemmk_kernel<3, 2048><<<4 * 128, 256, 0, stream>>>(
          h_c, wt2, b2, 512, 4, nullptr, out + r0 * 512, nullptr, x1b + r0 * 512, 0);
    }
  }
}

// Round 18
// 770.631 us; speedup vs baseline: 1.1018x; 1.0147x over previous
//
#include <hip/hip_runtime.h>
#include <hip/hip_bf16.h>

typedef __hip_bfloat16 bf16;
typedef short short4_t __attribute__((ext_vector_type(4)));
typedef short short8 __attribute__((ext_vector_type(8)));
typedef float f32x4 __attribute__((ext_vector_type(4)));

// static config
#define DIMC 512
#define HEADS_ 16
#define NTOK 65        // 64 window tokens + 1 time token
#define NWIN 64
#define NB 16
#define HID 2048
#define TOTROWS 66560  // 16*64*65
#define IMGROWS 65536  // 16*4096
#define ATT_CHUNK_WB 128
#define ATT_CHUNK_ROWS (ATT_CHUNK_WB * NTOK)  // 8320

// ---------------- helpers ----------------

__device__ __forceinline__ float b2f(short s) {
  unsigned int u = ((unsigned int)(unsigned short)s) << 16;
  float f; __builtin_memcpy(&f, &u, 4); return f;
}
__device__ __forceinline__ short f2s(float f) {
  bf16 b = __float2bfloat16(f);
  short s; __builtin_memcpy(&s, &b, 2); return s;
}

// async global->LDS, 16B per lane; LDS dest is wave-uniform base + lane*16
__device__ __forceinline__ void async_lds16(const bf16* g, bf16* l) {
  __builtin_amdgcn_global_load_lds(
      (const __attribute__((address_space(1))) unsigned int*)g,
      (__attribute__((address_space(3))) unsigned int*)l,
      16, 0, 0);
}

// per-wave LN stats over 512 elems (8 per lane)
__device__ __forceinline__ void wave_stats512(const float* v, float& m, float& rstd)
{
  float s = 0.0f, ss = 0.0f;
  #pragma unroll
  for (int e = 0; e < 8; ++e) { s += v[e]; ss += v[e] * v[e]; }
  #pragma unroll
  for (int o = 1; o < 64; o <<= 1) { s += __shfl_xor(s, o); ss += __shfl_xor(ss, o); }
  m = s * (1.0f / 512.0f);
  rstd = rsqrtf(ss * (1.0f / 512.0f) - m * m + 1e-5f);
}

// 8-op tanh-form GELU via sigmoid identity; max abs err ~3e-4
__device__ __forceinline__ float gelu_t(float v) {
  float v2 = v * v;
  float a  = fmaf(0.044715f, v2, 1.0f);
  float e  = __builtin_exp2f(-2.3022042f * (v * a));   // exp(-2z)
  return v * __builtin_amdgcn_rcpf(1.0f + e);
}

// ---------------- small kernels ----------------

__global__ __launch_bounds__(256) void time_emb_kernel(
    const float* __restrict__ emb, const float* __restrict__ W_emb,
    const float* __restrict__ b_emb, float* __restrict__ t)
{
  int b = blockIdx.x;
  int c = blockIdx.y * 256 + threadIdx.x;
  __shared__ float se[512];
  for (int k = threadIdx.x; k < 512; k += 256) {
    float e = emb[b * 512 + k];
    se[k] = e / (1.0f + expf(-e));
  }
  __syncthreads();
  float acc = b_emb[c];
  for (int k = 0; k < 512; ++k) acc += se[k] * W_emb[k * 512 + c];
  t[b * 512 + c] = acc;
}

// W (Kd x Nd) f32 -> Wt (Nd x Kd) bf16
__global__ void transpose_cast_kernel(const float* __restrict__ W, bf16* __restrict__ Wt,
                                      int Kd, int Nd)
{
  __shared__ float tile[32][33];
  int n0 = blockIdx.x * 32, k0 = blockIdx.y * 32;
  for (int r = threadIdx.y; r < 32; r += 8)
    tile[r][threadIdx.x] = W[(long)(k0 + r) * Nd + n0 + threadIdx.x];
  __syncthreads();
  for (int r = threadIdx.y; r < 32; r += 8)
    Wt[(long)(n0 + r) * Kd + k0 + threadIdx.x] = __float2bfloat16(tile[threadIdx.x][r]);
}

// combined bias+mask table: tbl[h][wtype][i(query) 80][t(key) 80] f32
__global__ __launch_bounds__(256) void bias_mask_kernel(
    const float* __restrict__ btab, float* __restrict__ tbl)
{
  int h = blockIdx.x, wt = blockIdx.y;
  for (int idx = threadIdx.x; idx < 6400; idx += 256) {
    int i = idx / 80, t = idx % 80;
    float v;
    if (t >= 65) v = -1e30f;
    else if (i >= 64 || t == 64) v = 0.0f;
    else {
      int rel = (((i >> 3) - (t >> 3) + 7) * 15) + ((i & 7) - (t & 7) + 7);
      v = btab[rel * HEADS_ + h];
      int rci = (wt & 2) ? (((i >> 3) < 4) ? 1 : 2) : 0;
      int cci = (wt & 1) ? (((i & 7) < 4) ? 1 : 2) : 0;
      int rct = (wt & 2) ? (((t >> 3) < 4) ? 1 : 2) : 0;
      int cct = (wt & 1) ? (((t & 7) < 4) ? 1 : 2) : 0;
      if (rci * 3 + cci != rct * 3 + cct) v -= 100.0f;
    }
    tbl[(h * 4 + wt) * 6400 + idx] = v;
  }
}

// LN1 + cyclic shift + window partition + time-token append -> xw bf16 (66560 x 512)
__global__ __launch_bounds__(256) void ln1_window_kernel(
    const float* __restrict__ x, const float* __restrict__ gamma,
    const float* __restrict__ beta, const float* __restrict__ t,
    bf16* __restrict__ xw)
{
  long r = (long)blockIdx.x * 4 + (threadIdx.x >> 6);   // 0..66559
  int lane = threadIdx.x & 63;
  int wb = (int)(r / NTOK), i = (int)(r % NTOK);
  int b = wb >> 6, w = wb & 63;
  bf16* out = xw + r * 512 + lane * 8;
  if (i == 64) {
    const float* tr = t + b * 512 + lane * 8;
    short8 o;
    #pragma unroll
    for (int e = 0; e < 8; ++e) o[e] = f2s(tr[e]);
    *(short8*)out = o;
    return;
  }
  int wh = w >> 3, ww = w & 7, ih = i >> 3, iw = i & 7;
  int hsrc = ((wh * 8 + ih) + 4) & 63;
  int wsrc = ((ww * 8 + iw) + 4) & 63;
  const float* xr = x + ((long)b * 4096 + hsrc * 64 + wsrc) * 512 + lane * 8;
  float v[8];
  *(f32x4*)&v[0] = *(const f32x4*)xr;
  *(f32x4*)&v[4] = *(const f32x4*)(xr + 4);
  float m, rstd;
  wave_stats512(v, m, rstd);
  const float* g = gamma + lane * 8;
  const float* bt = beta + lane * 8;
  short8 o;
  #pragma unroll
  for (int e = 0; e < 8; ++e) o[e] = f2s((v[e] - m) * rstd * g[e] + bt[e]);
  *(short8*)out = o;
}

// LN2 over x1b rows (bf16 in, bf16 out); one WAVE per row
__global__ __launch_bounds__(256) void ln2_kernel(
    const bf16* __restrict__ x1, const float* __restrict__ gamma,
    const float* __restrict__ beta, bf16* __restrict__ out)
{
  long r = (long)blockIdx.x * 4 + (threadIdx.x >> 6);
  int lane = threadIdx.x & 63;
  short8 xv = *(const short8*)(x1 + r * 512 + lane * 8);
  float v[8];
  #pragma unroll
  for (int e = 0; e < 8; ++e) v[e] = b2f(xv[e]);
  float m, rstd;
  wave_stats512(v, m, rstd);
  const float* g = gamma + lane * 8;
  const float* bt = beta + lane * 8;
  short8 o;
  #pragma unroll
  for (int e = 0; e < 8; ++e) o[e] = f2s((v[e] - m) * rstd * g[e] + bt[e]);
  *(short8*)(out + r * 512 + lane * 8) = o;
}

// ---------------- 256x256 8-wave 4-phase MFMA GEMM, half-tile counted vmcnt --
// As r17, but B-frags for BOTH halves are register-cached across the phase
// pair (bvh[2][2][2], +16 VGPR): ds_reads drop 32->24 per K-tile per wave
// (every fragment read exactly once); phase 3 issues no ds_reads.
// Sync/wait/stagger structure identical to r17 (verified).
template<int EPI, int K>
__global__ __launch_bounds__(512, 1) void gemm8p_kernel(
    const bf16* __restrict__ A, const bf16* __restrict__ Bt,
    const float* __restrict__ bias, int N, int nx,
    bf16* __restrict__ outB, float* __restrict__ outF,
    const float* __restrict__ xinF, const bf16* __restrict__ xinB, int rowOffset)
{
  constexpr int NKT = K / 64;
  __shared__ bf16 lds[8][128 * 64];    // [buf*4 + mat*2 + half]
  const int tid = threadIdx.x;
  const int lane = tid & 63, wv = tid >> 6;
  const int wm = wv >> 2, wn = wv & 3;
  const int fr = lane & 15, fg = lane >> 4;

  // bijective XCD swizzle (m204)
  const int nwg = gridDim.x, bid = blockIdx.x;
  const int q8 = nwg >> 3, rr8 = nwg & 7;
  const int xcd = bid & 7, idx = bid >> 3;
  const int sid = (xcd < rr8 ? xcd * (q8 + 1) : rr8 * (q8 + 1) + (xcd - rr8) * q8) + idx;
  const long row0 = (long)(sid / nx) * 256;
  const long col0 = (long)(sid % nx) * 256;

  const int rl = lane >> 3, sl = lane & 7;
  const int sls = sl ^ rl;                    // pre-swizzled global slot

  auto stageH = [&](int buf, int mat, int h, int kt) {
    const bf16* base = mat ? Bt : A;
    const long rb = (mat ? col0 : row0) + h * 128 + wv * 8 + rl;
    const bf16* src = base + rb * (long)K + kt + sls * 8;
    bf16* dst = &lds[buf * 4 + mat * 2 + h][(wv * 8) * 64];
    async_lds16(src, dst);
    async_lds16(src + 64 * (long)K, dst + 64 * 64);
  };
  auto fragA = [&](int buf, int h, int mi, int ks) -> short8 {
    int r = wm * 64 + mi * 16 + fr;
    return *(const short8*)((const char*)&lds[buf * 4 + h][0] + r * 128 + (((ks * 4 + fg) ^ (r & 7)) << 4));
  };
  auto fragB = [&](int buf, int h, int ni, int ks) -> short8 {
    int r = wn * 32 + ni * 16 + fr;
    return *(const short8*)((const char*)&lds[buf * 4 + 2 + h][0] + r * 128 + (((ks * 4 + fg) ^ (r & 7)) << 4));
  };

  f32x4 acc[8][4] = {};                 // [h*4+mi][nh*2+ni]
  short8 af[4][2], bvh[2][2][2];        // af: current A-half; bvh[nh][ni][ks]

  // prologue: tile 0 in steady stage order [Ah0, Bh0, Bh1, Ah1]
  stageH(0, 0, 0, 0); stageH(0, 1, 0, 0); stageH(0, 1, 1, 0); stageH(0, 0, 1, 0);

  for (int t = 0; t < NKT; ++t) {
    const int buf = t & 1, nb = buf ^ 1;
    const bool st = (t + 1 < NKT);
    const int kt2 = (t + 1) << 6;

    // phase 0: (mh0, nh0) — needs Ah0, Bh0 (oldest 4 loads)
    asm volatile("s_waitcnt vmcnt(4)" ::: "memory");
    __builtin_amdgcn_s_barrier();
    #pragma unroll
    for (int mi = 0; mi < 4; ++mi) { af[mi][0] = fragA(buf, 0, mi, 0); af[mi][1] = fragA(buf, 0, mi, 1); }
    #pragma unroll
    for (int ni = 0; ni < 2; ++ni) { bvh[0][ni][0] = fragB(buf, 0, ni, 0); bvh[0][ni][1] = fragB(buf, 0, ni, 1); }
    if (st) stageH(nb, 0, 0, kt2);            // Ah0'
    __builtin_amdgcn_s_setprio(1);
    #pragma unroll
    for (int mi = 0; mi < 4; ++mi)
      #pragma unroll
      for (int ni = 0; ni < 2; ++ni)
        #pragma unroll
        for (int ks = 0; ks < 2; ++ks)
          acc[mi][ni] = __builtin_amdgcn_mfma_f32_16x16x32_bf16(af[mi][ks], bvh[0][ni][ks], acc[mi][ni], 0, 0, 0);
    __builtin_amdgcn_s_setprio(0);

    // phase 1: (0,1) — needs Bh1
    if (st) asm volatile("s_waitcnt vmcnt(4)" ::: "memory");
    else    asm volatile("s_waitcnt vmcnt(2)" ::: "memory");
    __builtin_amdgcn_s_barrier();
    #pragma unroll
    for (int ni = 0; ni < 2; ++ni) { bvh[1][ni][0] = fragB(buf, 1, ni, 0); bvh[1][ni][1] = fragB(buf, 1, ni, 1); }
    if (st) stageH(nb, 1, 0, kt2);            // Bh0'
    __builtin_amdgcn_s_setprio(1);
    #pragma unroll
    for (int mi = 0; mi < 4; ++mi)
      #pragma unroll
      for (int ni = 0; ni < 2; ++ni)
        #pragma unroll
        for (int ks = 0; ks < 2; ++ks)
          acc[mi][2 + ni] = __builtin_amdgcn_mfma_f32_16x16x32_bf16(af[mi][ks], bvh[1][ni][ks], acc[mi][2 + ni], 0, 0, 0);
    __builtin_amdgcn_s_setprio(0);

    // phase 2: (1,0) — needs Ah1; B-halves already in registers
    if (st) asm volatile("s_waitcnt vmcnt(4)" ::: "memory");
    else    asm volatile("s_waitcnt vmcnt(0)" ::: "memory");
    __builtin_amdgcn_s_barrier();
    #pragma unroll
    for (int mi = 0; mi < 4; ++mi) { af[mi][0] = fragA(buf, 1, mi, 0); af[mi][1] = fragA(buf, 1, mi, 1); }
    if (st) stageH(nb, 1, 1, kt2);            // Bh1'
    __builtin_amdgcn_s_setprio(1);
    #pragma unroll
    for (int mi = 0; mi < 4; ++mi)
      #pragma unroll
      for (int ni = 0; ni < 2; ++ni)
        #pragma unroll
        for (int ks = 0; ks < 2; ++ks)
          acc[4 + mi][ni] = __builtin_amdgcn_mfma_f32_16x16x32_bf16(af[mi][ks], bvh[0][ni][ks], acc[4 + mi][ni], 0, 0, 0);
    __builtin_amdgcn_s_setprio(0);

    // phase 3: (1,1) — no ds_reads; everything in registers
    __builtin_amdgcn_s_barrier();
    if (st) stageH(nb, 0, 1, kt2);            // Ah1'
    __builtin_amdgcn_s_setprio(1);
    #pragma unroll
    for (int mi = 0; mi < 4; ++mi)
      #pragma unroll
      for (int ni = 0; ni < 2; ++ni)
        #pragma unroll
        for (int ks = 0; ks < 2; ++ks)
          acc[4 + mi][2 + ni] = __builtin_amdgcn_mfma_f32_16x16x32_bf16(af[mi][ks], bvh[1][ni][ks], acc[4 + mi][2 + ni], 0, 0, 0);
    __builtin_amdgcn_s_setprio(0);
  }

  if (EPI == 0 || EPI == 1) {
    // direct scalar epilogue (proven fastest for bf16 outputs, r15 A/B)
    float bs[2][2];
    #pragma unroll
    for (int nh = 0; nh < 2; ++nh)
      #pragma unroll
      for (int ni = 0; ni < 2; ++ni)
        bs[nh][ni] = bias[col0 + nh * 128 + wn * 32 + ni * 16 + fr];
    #pragma unroll
    for (int h = 0; h < 2; ++h)
      #pragma unroll
      for (int mi = 0; mi < 4; ++mi)
        #pragma unroll
        for (int j = 0; j < 4; ++j) {
          long rr = row0 + h * 128 + wm * 64 + mi * 16 + fg * 4 + j;
          #pragma unroll
          for (int nh = 0; nh < 2; ++nh)
            #pragma unroll
            for (int ni = 0; ni < 2; ++ni) {
              long cc = col0 + nh * 128 + wn * 32 + ni * 16 + fr;
              float v = acc[h * 4 + mi][nh * 2 + ni][j] + bs[nh][ni];
              if (EPI == 1) v = gelu_t(v);
              outB[rr * N + cc] = __float2bfloat16(v);
            }
        }
    return;
  }

  // EPI 2/3: LDS-transposed f32 epilogue in 4 groups of 64 rows
  __syncthreads();
  float* ep = (float*)&lds[0][0];          // 64*260*4 = 66.6 KB (< 128 KB)
  const int c64 = tid & 63, r8 = tid >> 6;
  const f32x4 b4 = *(const f32x4*)&bias[col0 + c64 * 4];
  #pragma unroll
  for (int g = 0; g < 4; ++g) {
    int h = g >> 1, wmg = g & 1;
    if (wm == wmg) {
      #pragma unroll
      for (int mi = 0; mi < 4; ++mi)
        #pragma unroll
        for (int nh = 0; nh < 2; ++nh)
          #pragma unroll
          for (int ni = 0; ni < 2; ++ni)
            #pragma unroll
            for (int j = 0; j < 4; ++j)
              ep[(mi * 16 + fg * 4 + j) * 260 + nh * 128 + wn * 32 + ni * 16 + fr] =
                  acc[h * 4 + mi][nh * 2 + ni][j];
    }
    __syncthreads();
    #pragma unroll
    for (int it = 0; it < 8; ++it) {
      int lrow = it * 8 + r8;
      long rr = row0 + h * 128 + wmg * 64 + lrow;
      f32x4 v = *(const f32x4*)&ep[lrow * 260 + c64 * 4];
      v += b4;
      if (EPI == 2) {
        int grow = rowOffset + (int)rr;
        int ii = grow % NTOK;
        if (ii != 64) {
          int wb = grow / NTOK;
          int b = wb >> 6, w = wb & 63;
          int wh = w >> 3, ww = w & 7, ih = ii >> 3, iw = ii & 7;
          int hh   = ((wh * 8 + ih) + 4) & 63;
          int wcol = ((ww * 8 + iw) + 4) & 63;
          long o = ((long)b * 4096 + hh * 64 + wcol) * 512 + col0 + c64 * 4;
          f32x4 xi = *(const f32x4*)&xinF[o];
          f32x4 x1 = xi + v;
          short4_t s4;
          #pragma unroll
          for (int e = 0; e < 4; ++e) s4[e] = f2s(x1[e]);
          *(short4_t*)&outB[o] = s4;       // x1b (bf16)
        }
      } else {
        long o = rr * N + col0 + c64 * 4;
        short4_t xv = *(const short4_t*)&xinB[o];
        f32x4 xf;
        #pragma unroll
        for (int e = 0; e < 4; ++e) xf[e] = b2f(xv[e]);
        *(f32x4*)&outF[o] = xf + v;        // final out (f32)
      }
    }
    __syncthreads();
  }
}

// ---------------- 128x128 fallback GEMM (r16, proven) ----------------
template<int EPI, int K>
__global__ __launch_bounds__(256, 3) void gemmk_kernel(
    const bf16* __restrict__ A, const bf16* __restrict__ Bt,
    const float* __restrict__ bias, int N, int nx,
    bf16* __restrict__ outB, float* __restrict__ outF,
    const float* __restrict__ xinF, const bf16* __restrict__ xinB, int rowOffset)
{
  constexpr int NKT = K / 32;
  static_assert((NKT - 1) % 3 == 0, "triplet peel needs NKT = 3m+1");
  __shared__ bf16 ldsbuf[6 * 128 * 32];
  bf16* const lAp = ldsbuf;
  bf16* const lBp = ldsbuf + 3 * 4096;
  const int tid = threadIdx.x;
  const int lane = tid & 63, wv = tid >> 6;
  const int wm = wv >> 1, wn = wv & 1;
  const int fr = lane & 15, fg = lane >> 4;

  const int nwg = gridDim.x, bid = blockIdx.x;
  const int q8 = nwg >> 3, rr8 = nwg & 7;
  const int xcd = bid & 7, idx = bid >> 3;
  const int sid = (xcd < rr8 ? xcd * (q8 + 1) : rr8 * (q8 + 1) + (xcd - rr8) * q8) + idx;
  const long row0 = (long)(sid / nx) * 128;
  const long col0 = (long)(sid % nx) * 128;

  const int rl = lane >> 2, sp = lane & 3;
  const int s = sp ^ ((rl >> 1) & 3);
  const bf16* ga0 = A  + (row0 + wv * 32 + rl) * (long)K + s * 8;
  const bf16* ga1 = ga0 + 16 * (long)K;
  const bf16* gb0 = Bt + (col0 + wv * 32 + rl) * (long)K + s * 8;
  const bf16* gb1 = gb0 + 16 * (long)K;

  f32x4 acc[4][4] = {};
  const int swr = (fg ^ ((fr >> 1) & 3)) << 4;

  auto stage = [&](int buf, int t) {
    const long o = (long)t * 32;
    async_lds16(ga0 + o, &lAp[buf * 4096 + (wv * 32) * 32]);
    async_lds16(ga1 + o, &lAp[buf * 4096 + (wv * 32 + 16) * 32]);
    async_lds16(gb0 + o, &lBp[buf * 4096 + (wv * 32) * 32]);
    async_lds16(gb1 + o, &lBp[buf * 4096 + (wv * 32 + 16) * 32]);
  };

  stage(0, 0);
  stage(1, 1);

#define GBODY(BUF)                                                              \
  do {                                                                          \
    if (t + 1 < NKT) asm volatile("s_waitcnt vmcnt(4)" ::: "memory");           \
    else             asm volatile("s_waitcnt vmcnt(0)" ::: "memory");           \
    __builtin_amdgcn_s_barrier();                                               \
    short8 bfv[4], af[4];                                                       \
    _Pragma("unroll")                                                           \
    for (int ni = 0; ni < 4; ++ni)                                              \
      bfv[ni] = *(const short8*)((const char*)&lBp[(BUF) * 4096] +              \
                                 (wn * 64 + ni * 16 + fr) * 64 + swr);          \
    _Pragma("unroll")                                                           \
    for (int mi = 0; mi < 4; ++mi)                                              \
      af[mi] = *(const short8*)((const char*)&lAp[(BUF) * 4096] +               \
                                (wm * 64 + mi * 16 + fr) * 64 + swr);           \
    if (t + 2 < NKT) stage(((BUF) + 2) % 3, t + 2);                             \
    __builtin_amdgcn_s_setprio(1);                                              \
    _Pragma("unroll")                                                           \
    for (int mi = 0; mi < 4; ++mi)                                              \
      _Pragma("unroll")                                                         \
      for (int ni = 0; ni < 4; ++ni)                                            \
        acc[mi][ni] = __builtin_amdgcn_mfma_f32_16x16x32_bf16(                  \
            af[mi], bfv[ni], acc[mi][ni], 0, 0, 0);                             \
    __builtin_amdgcn_s_setprio(0);                                              \
    ++t;                                                                        \
  } while (0)

  int t = 0;
  GBODY(0);
  for (int g = 0; g < (NKT - 1) / 3; ++g) {
    GBODY(1);
    GBODY(2);
    GBODY(0);
  }
#undef GBODY

  if (EPI == 2 || EPI == 3) {
    __syncthreads();
    float* ep = (float*)ldsbuf;
    const int l31 = lane & 31, lr2 = lane >> 5;
    const f32x4 b4 = *(const f32x4*)&bias[col0 + l31 * 4];
    #pragma unroll
    for (int h = 0; h < 2; ++h) {
      if (wm == h) {
        #pragma unroll
        for (int mi = 0; mi < 4; ++mi)
          #pragma unroll
          for (int ni = 0; ni < 4; ++ni)
            #pragma unroll
            for (int j = 0; j < 4; ++j)
              ep[(mi * 16 + fg * 4 + j) * 132 + wn * 64 + ni * 16 + fr] = acc[mi][ni][j];
      }
      __syncthreads();
      #pragma unroll
      for (int it = 0; it < 8; ++it) {
        int lrow = it * 8 + wv * 2 + lr2;
        long rr = row0 + h * 64 + lrow;
        f32x4 v = *(const f32x4*)&ep[lrow * 132 + l31 * 4];
        v += b4;
        if (EPI == 2) {
          int grow = rowOffset + (int)rr;
          int ii = grow % NTOK;
          if (ii != 64) {
            int wb = grow / NTOK;
            int b = wb >> 6, w = wb & 63;
            int wh = w >> 3, ww = w & 7, ih = ii >> 3, iw = ii & 7;
            int hh   = ((wh * 8 + ih) + 4) & 63;
            int wcol = ((ww * 8 + iw) + 4) & 63;
            long o = ((long)b * 4096 + hh * 64 + wcol) * 512 + col0 + l31 * 4;
            f32x4 xi = *(const f32x4*)&xinF[o];
            f32x4 x1 = xi + v;
            short4_t s4;
            #pragma unroll
            for (int e = 0; e < 4; ++e) s4[e] = f2s(x1[e]);
            *(short4_t*)&outB[o] = s4;
          }
        } else {
          long o = rr * N + col0 + l31 * 4;
          short4_t xv = *(const short4_t*)&xinB[o];
          f32x4 xf;
          #pragma unroll
          for (int e = 0; e < 4; ++e) xf[e] = b2f(xv[e]);
          *(f32x4*)&outF[o] = xf + v;
        }
      }
      __syncthreads();
    }
    return;
  }

  float bs[4];
  #pragma unroll
  for (int ni = 0; ni < 4; ++ni) bs[ni] = bias[col0 + wn * 64 + ni * 16 + fr];
  #pragma unroll
  for (int mi = 0; mi < 4; ++mi) {
    #pragma unroll
    for (int j = 0; j < 4; ++j) {
      long rr = row0 + wm * 64 + mi * 16 + fg * 4 + j;
      #pragma unroll
      for (int ni = 0; ni < 4; ++ni) {
        long cc = col0 + wn * 64 + ni * 16 + fr;
        float v = acc[mi][ni][j] + bs[ni];
        if (EPI == 0) {
          outB[rr * N + cc] = __float2bfloat16(v);
        } else {
          outB[rr * N + cc] = __float2bfloat16(gelu_t(v));
        }
      }
    }
  }
}

// ---------------- MFMA windowed attention: one wave per (window-batch, head) ----
__global__ __launch_bounds__(64, 2) void attn_mfma_kernel(
    const bf16* __restrict__ qkv, bf16* __restrict__ attnO,
    const float* __restrict__ tbl, int wb0)
{
  __shared__ bf16 P[80 * 104];
  const int lwb = blockIdx.x, h = blockIdx.y;
  const int lane = threadIdx.x;
  const int fr = lane & 15, g = lane >> 4;
  const float scale = 0.17677669529663687f;   // 1/sqrt(32)
  const bf16* base = qkv + (long)lwb * 65 * 1536 + h * 32 + g * 8;

  for (int idx = lane; idx < 240; idx += 64) {
    int i = idx / 3, sl = idx % 3;
    *(short8*)&P[i * 104 + 80 + sl * 8] = (short8){0, 0, 0, 0, 0, 0, 0, 0};
  }

  short8 bq[5];
  #pragma unroll
  for (int tn = 0; tn < 5; ++tn) {
    int qr = tn * 16 + fr; qr = qr > 64 ? 64 : qr;
    bq[tn] = *(const short8*)(base + (long)qr * 1536);
  }

  f32x4 acc[5][5];
  #pragma unroll
  for (int tm = 0; tm < 5; ++tm) {
    int kr = tm * 16 + fr; kr = kr > 64 ? 64 : kr;
    short8 ak = *(const short8*)(base + 512 + (long)kr * 1536);
    #pragma unroll
    for (int tn = 0; tn < 5; ++tn)
      acc[tm][tn] = __builtin_amdgcn_mfma_f32_16x16x32_bf16(
          ak, bq[tn], (f32x4){0.0f, 0.0f, 0.0f, 0.0f}, 0, 0, 0);
  }

  const int w = (wb0 + lwb) & 63;
  const int wt = (((w >> 3) == 7) ? 2 : 0) + (((w & 7) == 7) ? 1 : 0);
  const float* tp = tbl + (h * 4 + wt) * 6400;
  #pragma unroll
  for (int tn = 0; tn < 5; ++tn) {
    const int i = tn * 16 + fr;
    const float* ti = tp + i * 80 + g * 4;
    float m = -3.0e38f;
    #pragma unroll
    for (int tm = 0; tm < 5; ++tm) {
      f32x4 bvv = *(const f32x4*)(ti + tm * 16);
      #pragma unroll
      for (int r = 0; r < 4; ++r) {
        float sv = fmaf(acc[tm][tn][r], scale, bvv[r]);
        acc[tm][tn][r] = sv;
        m = fmaxf(m, sv);
      }
    }
    m = fmaxf(m, __shfl_xor(m, 16));
    m = fmaxf(m, __shfl_xor(m, 32));
    float l = 0.0f;
    #pragma unroll
    for (int tm = 0; tm < 5; ++tm)
      #pragma unroll
      for (int r = 0; r < 4; ++r) {
        float e = __expf(acc[tm][tn][r] - m);
        acc[tm][tn][r] = e;
        l += e;
      }
    l += __shfl_xor(l, 16);
    l += __shfl_xor(l, 32);
    float inv = 1.0f / l;
    #pragma unroll
    for (int tm = 0; tm < 5; ++tm) {
      short4_t pk;
      #pragma unroll
      for (int r = 0; r < 4; ++r) pk[r] = f2s(acc[tm][tn][r] * inv);
      *(short4_t*)&P[i * 104 + tm * 16 + g * 4] = pk;
    }
  }

  const bf16* vbase = qkv + (long)lwb * 65 * 1536 + 1024 + h * 32;
  f32x4 oacc[2][5] = {};
  #pragma unroll
  for (int kt = 0; kt < 3; ++kt) {
    short8 bp[5];
    #pragma unroll
    for (int tn = 0; tn < 5; ++tn)
      bp[tn] = *(const short8*)&P[(tn * 16 + fr) * 104 + kt * 32 + g * 8];
    #pragma unroll
    for (int ma = 0; ma < 2; ++ma) {
      short8 av;
      #pragma unroll
      for (int e = 0; e < 8; ++e) {
        int vr = kt * 32 + g * 8 + e; vr = vr > 64 ? 64 : vr;
        av[e] = *(const short*)(vbase + (long)vr * 1536 + ma * 16 + fr);
      }
      #pragma unroll
      for (int tn = 0; tn < 5; ++tn)
        oacc[ma][tn] = __builtin_amdgcn_mfma_f32_16x16x32_bf16(
            av, bp[tn], oacc[ma][tn], 0, 0, 0);
    }
  }

  #pragma unroll
  for (int tn = 0; tn < 5; ++tn) {
    int i = tn * 16 + fr;
    if (i < 65) {
      bf16* op = attnO + (long)(lwb * 65 + i) * 512 + h * 32 + g * 4;
      #pragma unroll
      for (int ma = 0; ma < 2; ++ma) {
        short4_t o4;
        #pragma unroll
        for (int r = 0; r < 4; ++r) o4[r] = f2s(oacc[ma][tn][r]);
        *(short4_t*)(op + ma * 16) = o4;
      }
    }
  }
}

// ---------------- host ----------------

extern "C" void kernel_launch(void* const* d_in, const int* in_sizes, int n_in,
                              void* d_out, int out_size, void* d_ws, size_t ws_size,
                              hipStream_t stream)
{
  const float* x      = (const float*)d_in[0];
  const float* emb    = (const float*)d_in[1];
  const float* gamma1 = (const float*)d_in[2];
  const float* beta1  = (const float*)d_in[3];
  const float* W_emb  = (const float*)d_in[4];
  const float* b_emb  = (const float*)d_in[5];
  const float* W_qkv  = (const float*)d_in[6];
  const float* b_qkv  = (const float*)d_in[7];
  const float* btab   = (const float*)d_in[8];
  const float* W_proj = (const float*)d_in[9];
  const float* b_proj = (const float*)d_in[10];
  const float* gamma2 = (const float*)d_in[11];
  const float* beta2  = (const float*)d_in[12];
  const float* W1     = (const float*)d_in[13];
  const float* b1     = (const float*)d_in[14];
  const float* W2     = (const float*)d_in[15];
  const float* b2     = (const float*)d_in[16];
  float* out = (float*)d_out;
  (void)n_in; (void)in_sizes; (void)out_size;

  char* ws = (char*)d_ws;
  size_t off = 0;
  auto alloc = [&](size_t bytes) -> char* {
    char* p = ws + off;
    off += (bytes + 255) & ~(size_t)255;
    return p;
  };
  bf16* wt_qkv  = (bf16*)alloc((size_t)1536 * 512 * 2);
  bf16* wt_proj = (bf16*)alloc((size_t)512 * 512 * 2);
  bf16* wt1     = (bf16*)alloc((size_t)2048 * 512 * 2);
  bf16* wt2     = (bf16*)alloc((size_t)512 * 2048 * 2);
  float* tvec   = (float*)alloc((size_t)16 * 512 * 4);
  float* tbl    = (float*)alloc((size_t)16 * 4 * 6400 * 4);

  const size_t sz_xw    = (size_t)TOTROWS * 512 * 2;
  const size_t sz_qkv   = (size_t)TOTROWS * 1536 * 2;
  const size_t sz_attnO = (size_t)TOTROWS * 512 * 2;
  const bool big = ws_size >= off + sz_xw + sz_qkv + sz_attnO + (4u << 20);

  transpose_cast_kernel<<<dim3(1536 / 32, 512 / 32), dim3(32, 8), 0, stream>>>(W_qkv, wt_qkv, 512, 1536);
  transpose_cast_kernel<<<dim3(512 / 32, 512 / 32),  dim3(32, 8), 0, stream>>>(W_proj, wt_proj, 512, 512);
  transpose_cast_kernel<<<dim3(2048 / 32, 512 / 32), dim3(32, 8), 0, stream>>>(W1, wt1, 512, 2048);
  transpose_cast_kernel<<<dim3(512 / 32, 2048 / 32), dim3(32, 8), 0, stream>>>(W2, wt2, 2048, 512);
  time_emb_kernel<<<dim3(16, 2), 256, 0, stream>>>(emb, W_emb, b_emb, tvec);
  bias_mask_kernel<<<dim3(16, 4), 256, 0, stream>>>(btab, tbl);

  if (big) {
    char* regionA = alloc(sz_xw);       // xw -> later x1b
    char* regionQ = alloc(sz_qkv);      // qkv -> later h_c + ln2b
    bf16* attnO   = (bf16*)alloc(sz_attnO);
    bf16* xw   = (bf16*)regionA;
    bf16* x1b  = (bf16*)regionA;
    bf16* qkv  = (bf16*)regionQ;
    bf16* h_c  = (bf16*)regionQ;
    bf16* ln2b = (bf16*)(regionQ + (size_t)32768 * 2048 * 2);

    ln1_window_kernel<<<TOTROWS / 4, 256, 0, stream>>>(x, gamma1, beta1, tvec, xw);
    // qkv: M=66560 (260x256), N=1536 (6x256), K=512
    gemm8p_kernel<0, 512><<<6 * 260, 512, 0, stream>>>(
        xw, wt_qkv, b_qkv, 1536, 6, qkv, nullptr, nullptr, nullptr, 0);
    attn_mfma_kernel<<<dim3(NB * NWIN, HEADS_), 64, 0, stream>>>(qkv, attnO, tbl, 0);
    // proj: x1b = bf16(x + C), scatter
    gemm8p_kernel<2, 512><<<2 * 260, 512, 0, stream>>>(
        attnO, wt_proj, b_proj, 512, 2, x1b, nullptr, x, nullptr, 0);
    ln2_kernel<<<IMGROWS / 4, 256, 0, stream>>>(x1b, gamma2, beta2, ln2b);
    for (int mc = 0; mc < 2; ++mc) {
      long r0 = (long)mc * 32768;
      gemm8p_kernel<1, 512><<<8 * 128, 512, 0, stream>>>(
          ln2b + r0 * 512, wt1, b1, 2048, 8, h_c, nullptr, nullptr, nullptr, 0);
      gemm8p_kernel<3, 2048><<<2 * 128, 512, 0, stream>>>(
          h_c, wt2, b2, 512, 2, nullptr, out + r0 * 512, nullptr, x1b + r0 * 512, 0);
    }
  } else {
    // chunked fallback (proven gemmk path)
    char* regionA = alloc(sz_xw);
    bf16* xw   = (bf16*)regionA;
    bf16* x1b  = (bf16*)regionA;
    bf16* qkv_c = (bf16*)alloc((size_t)ATT_CHUNK_ROWS * 1536 * 2);
    char* regionB = alloc(sz_attnO);
    bf16* attnO = (bf16*)regionB;
    bf16* ln2b  = (bf16*)regionB;
    bf16* h_c   = (bf16*)alloc((size_t)16384 * 2048 * 2);

    ln1_window_kernel<<<TOTROWS / 4, 256, 0, stream>>>(x, gamma1, beta1, tvec, xw);
    for (int ac = 0; ac < 8; ++ac) {
      long r0 = (long)ac * ATT_CHUNK_ROWS;
      gemmk_kernel<0, 512><<<12 * 65, 256, 0, stream>>>(
          xw + r0 * 512, wt_qkv, b_qkv, 1536, 12, qkv_c, nullptr, nullptr, nullptr, 0);
      attn_mfma_kernel<<<dim3(ATT_CHUNK_WB, HEADS_), 64, 0, stream>>>(
          qkv_c, attnO + r0 * 512, tbl, ac * ATT_CHUNK_WB);
    }
    gemmk_kernel<2, 512><<<4 * 520, 256, 0, stream>>>(
        attnO, wt_proj, b_proj, 512, 4, x1b, nullptr, x, nullptr, 0);
    ln2_kernel<<<IMGROWS / 4, 256, 0, stream>>>(x1b, gamma2, beta2, ln2b);
    for (int mc = 0; mc < 4; ++mc) {
      long r0 = (long)mc * 16384;
      gemmk_kernel<1, 512><<<16 * 128, 256, 0, stream>>>(
          ln2b + r0 * 512, wt1, b1, 2048, 16, h_c, nullptr, nullptr, nullptr, 0);
      gemmk_kernel<3, 2048><<<4 * 128, 256, 0, stream>>>(
          h_c, wt2, b2, 512, 4, nullptr, out + r0 * 512, nullptr, x1b + r0 * 512, 0);
    }
  }
}

// Round 19
// 767.973 us; speedup vs baseline: 1.1056x; 1.0035x over previous
//
#include <hip/hip_runtime.h>
#include <hip/hip_bf16.h>

typedef __hip_bfloat16 bf16;
typedef short short4_t __attribute__((ext_vector_type(4)));
typedef short short8 __attribute__((ext_vector_type(8)));
typedef float f32x4 __attribute__((ext_vector_type(4)));

// static config
#define DIMC 512
#define HEADS_ 16
#define NTOK 65        // 64 window tokens + 1 time token
#define NWIN 64
#define NB 16
#define HID 2048
#define TOTROWS 66560  // 16*64*65
#define IMGROWS 65536  // 16*4096
#define ATT_CHUNK_WB 128
#define ATT_CHUNK_ROWS (ATT_CHUNK_WB * NTOK)  // 8320

// ---------------- helpers ----------------

__device__ __forceinline__ float b2f(short s) {
  unsigned int u = ((unsigned int)(unsigned short)s) << 16;
  float f; __builtin_memcpy(&f, &u, 4); return f;
}
__device__ __forceinline__ short f2s(float f) {
  bf16 b = __float2bfloat16(f);
  short s; __builtin_memcpy(&s, &b, 2); return s;
}

// async global->LDS, 16B per lane; LDS dest is wave-uniform base + lane*16
__device__ __forceinline__ void async_lds16(const bf16* g, bf16* l) {
  __builtin_amdgcn_global_load_lds(
      (const __attribute__((address_space(1))) unsigned int*)g,
      (__attribute__((address_space(3))) unsigned int*)l,
      16, 0, 0);
}

// per-wave LN stats over 512 elems (8 per lane)
__device__ __forceinline__ void wave_stats512(const float* v, float& m, float& rstd)
{
  float s = 0.0f, ss = 0.0f;
  #pragma unroll
  for (int e = 0; e < 8; ++e) { s += v[e]; ss += v[e] * v[e]; }
  #pragma unroll
  for (int o = 1; o < 64; o <<= 1) { s += __shfl_xor(s, o); ss += __shfl_xor(ss, o); }
  m = s * (1.0f / 512.0f);
  rstd = rsqrtf(ss * (1.0f / 512.0f) - m * m + 1e-5f);
}

// 8-op tanh-form GELU via sigmoid identity; max abs err ~3e-4
__device__ __forceinline__ float gelu_t(float v) {
  float v2 = v * v;
  float a  = fmaf(0.044715f, v2, 1.0f);
  float e  = __builtin_exp2f(-2.3022042f * (v * a));   // exp(-2z)
  return v * __builtin_amdgcn_rcpf(1.0f + e);
}

// ---------------- small kernels ----------------

__global__ __launch_bounds__(256) void time_emb_kernel(
    const float* __restrict__ emb, const float* __restrict__ W_emb,
    const float* __restrict__ b_emb, float* __restrict__ t)
{
  int b = blockIdx.x;
  int c = blockIdx.y * 256 + threadIdx.x;
  __shared__ float se[512];
  for (int k = threadIdx.x; k < 512; k += 256) {
    float e = emb[b * 512 + k];
    se[k] = e / (1.0f + expf(-e));
  }
  __syncthreads();
  float acc = b_emb[c];
  for (int k = 0; k < 512; ++k) acc += se[k] * W_emb[k * 512 + c];
  t[b * 512 + c] = acc;
}

// W (Kd x Nd) f32 -> Wt (Nd x Kd) bf16
__global__ void transpose_cast_kernel(const float* __restrict__ W, bf16* __restrict__ Wt,
                                      int Kd, int Nd)
{
  __shared__ float tile[32][33];
  int n0 = blockIdx.x * 32, k0 = blockIdx.y * 32;
  for (int r = threadIdx.y; r < 32; r += 8)
    tile[r][threadIdx.x] = W[(long)(k0 + r) * Nd + n0 + threadIdx.x];
  __syncthreads();
  for (int r = threadIdx.y; r < 32; r += 8)
    Wt[(long)(n0 + r) * Kd + k0 + threadIdx.x] = __float2bfloat16(tile[threadIdx.x][r]);
}

// combined bias+mask table: tbl[h][wtype][i(query) 80][t(key) 80] f32
__global__ __launch_bounds__(256) void bias_mask_kernel(
    const float* __restrict__ btab, float* __restrict__ tbl)
{
  int h = blockIdx.x, wt = blockIdx.y;
  for (int idx = threadIdx.x; idx < 6400; idx += 256) {
    int i = idx / 80, t = idx % 80;
    float v;
    if (t >= 65) v = -1e30f;
    else if (i >= 64 || t == 64) v = 0.0f;
    else {
      int rel = (((i >> 3) - (t >> 3) + 7) * 15) + ((i & 7) - (t & 7) + 7);
      v = btab[rel * HEADS_ + h];
      int rci = (wt & 2) ? (((i >> 3) < 4) ? 1 : 2) : 0;
      int cci = (wt & 1) ? (((i & 7) < 4) ? 1 : 2) : 0;
      int rct = (wt & 2) ? (((t >> 3) < 4) ? 1 : 2) : 0;
      int cct = (wt & 1) ? (((t & 7) < 4) ? 1 : 2) : 0;
      if (rci * 3 + cci != rct * 3 + cct) v -= 100.0f;
    }
    tbl[(h * 4 + wt) * 6400 + idx] = v;
  }
}

// LN1 + cyclic shift + window partition + time-token append -> xw bf16 (66560 x 512)
__global__ __launch_bounds__(256) void ln1_window_kernel(
    const float* __restrict__ x, const float* __restrict__ gamma,
    const float* __restrict__ beta, const float* __restrict__ t,
    bf16* __restrict__ xw)
{
  long r = (long)blockIdx.x * 4 + (threadIdx.x >> 6);   // 0..66559
  int lane = threadIdx.x & 63;
  int wb = (int)(r / NTOK), i = (int)(r % NTOK);
  int b = wb >> 6, w = wb & 63;
  bf16* out = xw + r * 512 + lane * 8;
  if (i == 64) {
    const float* tr = t + b * 512 + lane * 8;
    short8 o;
    #pragma unroll
    for (int e = 0; e < 8; ++e) o[e] = f2s(tr[e]);
    *(short8*)out = o;
    return;
  }
  int wh = w >> 3, ww = w & 7, ih = i >> 3, iw = i & 7;
  int hsrc = ((wh * 8 + ih) + 4) & 63;
  int wsrc = ((ww * 8 + iw) + 4) & 63;
  const float* xr = x + ((long)b * 4096 + hsrc * 64 + wsrc) * 512 + lane * 8;
  float v[8];
  *(f32x4*)&v[0] = *(const f32x4*)xr;
  *(f32x4*)&v[4] = *(const f32x4*)(xr + 4);
  float m, rstd;
  wave_stats512(v, m, rstd);
  const float* g = gamma + lane * 8;
  const float* bt = beta + lane * 8;
  short8 o;
  #pragma unroll
  for (int e = 0; e < 8; ++e) o[e] = f2s((v[e] - m) * rstd * g[e] + bt[e]);
  *(short8*)out = o;
}

// LN2 over x1b rows (bf16 in, bf16 out); one WAVE per row
__global__ __launch_bounds__(256) void ln2_kernel(
    const bf16* __restrict__ x1, const float* __restrict__ gamma,
    const float* __restrict__ beta, bf16* __restrict__ out)
{
  long r = (long)blockIdx.x * 4 + (threadIdx.x >> 6);
  int lane = threadIdx.x & 63;
  short8 xv = *(const short8*)(x1 + r * 512 + lane * 8);
  float v[8];
  #pragma unroll
  for (int e = 0; e < 8; ++e) v[e] = b2f(xv[e]);
  float m, rstd;
  wave_stats512(v, m, rstd);
  const float* g = gamma + lane * 8;
  const float* bt = beta + lane * 8;
  short8 o;
  #pragma unroll
  for (int e = 0; e < 8; ++e) o[e] = f2s((v[e] - m) * rstd * g[e] + bt[e]);
  *(short8*)(out + r * 512 + lane * 8) = o;
}

// ---------------- 256x256 8-wave 3-phase MFMA GEMM, half-tile counted vmcnt --
// As r18 (B-frags register-cached across the phase pair) but phases 2+3 are
// MERGED: 3 barriers per K-tile instead of 4. Wait-count audit: steady p0/p1/p2
// all vmcnt(4) (2 half-tiles = 4 loads allowed in flight), tail 4/2/0 — same
// queue discipline as r17/r18.
template<int EPI, int K>
__global__ __launch_bounds__(512, 1) void gemm8p_kernel(
    const bf16* __restrict__ A, const bf16* __restrict__ Bt,
    const float* __restrict__ bias, int N, int nx,
    bf16* __restrict__ outB, float* __restrict__ outF,
    const float* __restrict__ xinF, const bf16* __restrict__ xinB, int rowOffset)
{
  constexpr int NKT = K / 64;
  __shared__ bf16 lds[8][128 * 64];    // [buf*4 + mat*2 + half]
  const int tid = threadIdx.x;
  const int lane = tid & 63, wv = tid >> 6;
  const int wm = wv >> 2, wn = wv & 3;
  const int fr = lane & 15, fg = lane >> 4;

  // bijective XCD swizzle (m204)
  const int nwg = gridDim.x, bid = blockIdx.x;
  const int q8 = nwg >> 3, rr8 = nwg & 7;
  const int xcd = bid & 7, idx = bid >> 3;
  const int sid = (xcd < rr8 ? xcd * (q8 + 1) : rr8 * (q8 + 1) + (xcd - rr8) * q8) + idx;
  const long row0 = (long)(sid / nx) * 256;
  const long col0 = (long)(sid % nx) * 256;

  const int rl = lane >> 3, sl = lane & 7;
  const int sls = sl ^ rl;                    // pre-swizzled global slot

  auto stageH = [&](int buf, int mat, int h, int kt) {
    const bf16* base = mat ? Bt : A;
    const long rb = (mat ? col0 : row0) + h * 128 + wv * 8 + rl;
    const bf16* src = base + rb * (long)K + kt + sls * 8;
    bf16* dst = &lds[buf * 4 + mat * 2 + h][(wv * 8) * 64];
    async_lds16(src, dst);
    async_lds16(src + 64 * (long)K, dst + 64 * 64);
  };
  auto fragA = [&](int buf, int h, int mi, int ks) -> short8 {
    int r = wm * 64 + mi * 16 + fr;
    return *(const short8*)((const char*)&lds[buf * 4 + h][0] + r * 128 + (((ks * 4 + fg) ^ (r & 7)) << 4));
  };
  auto fragB = [&](int buf, int h, int ni, int ks) -> short8 {
    int r = wn * 32 + ni * 16 + fr;
    return *(const short8*)((const char*)&lds[buf * 4 + 2 + h][0] + r * 128 + (((ks * 4 + fg) ^ (r & 7)) << 4));
  };

  f32x4 acc[8][4] = {};                 // [h*4+mi][nh*2+ni]
  short8 af[4][2], bvh[2][2][2];        // af: current A-half; bvh[nh][ni][ks]

  // prologue: tile 0 in steady stage order [Ah0, Bh0, Bh1, Ah1]
  stageH(0, 0, 0, 0); stageH(0, 1, 0, 0); stageH(0, 1, 1, 0); stageH(0, 0, 1, 0);

  for (int t = 0; t < NKT; ++t) {
    const int buf = t & 1, nb = buf ^ 1;
    const bool st = (t + 1 < NKT);
    const int kt2 = (t + 1) << 6;

    // phase 0: (mh0, nh0) — needs Ah0, Bh0 (oldest 4 loads)
    asm volatile("s_waitcnt vmcnt(4)" ::: "memory");
    __builtin_amdgcn_s_barrier();
    #pragma unroll
    for (int mi = 0; mi < 4; ++mi) { af[mi][0] = fragA(buf, 0, mi, 0); af[mi][1] = fragA(buf, 0, mi, 1); }
    #pragma unroll
    for (int ni = 0; ni < 2; ++ni) { bvh[0][ni][0] = fragB(buf, 0, ni, 0); bvh[0][ni][1] = fragB(buf, 0, ni, 1); }
    if (st) stageH(nb, 0, 0, kt2);            // Ah0'
    __builtin_amdgcn_s_setprio(1);
    #pragma unroll
    for (int mi = 0; mi < 4; ++mi)
      #pragma unroll
      for (int ni = 0; ni < 2; ++ni)
        #pragma unroll
        for (int ks = 0; ks < 2; ++ks)
          acc[mi][ni] = __builtin_amdgcn_mfma_f32_16x16x32_bf16(af[mi][ks], bvh[0][ni][ks], acc[mi][ni], 0, 0, 0);
    __builtin_amdgcn_s_setprio(0);

    // phase 1: (0,1) — needs Bh1
    if (st) asm volatile("s_waitcnt vmcnt(4)" ::: "memory");
    else    asm volatile("s_waitcnt vmcnt(2)" ::: "memory");
    __builtin_amdgcn_s_barrier();
    #pragma unroll
    for (int ni = 0; ni < 2; ++ni) { bvh[1][ni][0] = fragB(buf, 1, ni, 0); bvh[1][ni][1] = fragB(buf, 1, ni, 1); }
    if (st) stageH(nb, 1, 0, kt2);            // Bh0'
    __builtin_amdgcn_s_setprio(1);
    #pragma unroll
    for (int mi = 0; mi < 4; ++mi)
      #pragma unroll
      for (int ni = 0; ni < 2; ++ni)
        #pragma unroll
        for (int ks = 0; ks < 2; ++ks)
          acc[mi][2 + ni] = __builtin_amdgcn_mfma_f32_16x16x32_bf16(af[mi][ks], bvh[1][ni][ks], acc[mi][2 + ni], 0, 0, 0);
    __builtin_amdgcn_s_setprio(0);

    // phase 2 (merged 2+3): (1,0) + (1,1) — needs Ah1; B already in registers
    if (st) asm volatile("s_waitcnt vmcnt(4)" ::: "memory");
    else    asm volatile("s_waitcnt vmcnt(0)" ::: "memory");
    __builtin_amdgcn_s_barrier();
    #pragma unroll
    for (int mi = 0; mi < 4; ++mi) { af[mi][0] = fragA(buf, 1, mi, 0); af[mi][1] = fragA(buf, 1, mi, 1); }
    if (st) { stageH(nb, 1, 1, kt2); stageH(nb, 0, 1, kt2); }   // Bh1', Ah1'
    __builtin_amdgcn_s_setprio(1);
    #pragma unroll
    for (int mi = 0; mi < 4; ++mi)
      #pragma unroll
      for (int ni = 0; ni < 2; ++ni)
        #pragma unroll
        for (int ks = 0; ks < 2; ++ks)
          acc[4 + mi][ni] = __builtin_amdgcn_mfma_f32_16x16x32_bf16(af[mi][ks], bvh[0][ni][ks], acc[4 + mi][ni], 0, 0, 0);
    #pragma unroll
    for (int mi = 0; mi < 4; ++mi)
      #pragma unroll
      for (int ni = 0; ni < 2; ++ni)
        #pragma unroll
        for (int ks = 0; ks < 2; ++ks)
          acc[4 + mi][2 + ni] = __builtin_amdgcn_mfma_f32_16x16x32_bf16(af[mi][ks], bvh[1][ni][ks], acc[4 + mi][2 + ni], 0, 0, 0);
    __builtin_amdgcn_s_setprio(0);
  }

  if (EPI == 0 || EPI == 1) {
    // direct scalar epilogue (proven fastest for bf16 outputs, r15 A/B)
    float bs[2][2];
    #pragma unroll
    for (int nh = 0; nh < 2; ++nh)
      #pragma unroll
      for (int ni = 0; ni < 2; ++ni)
        bs[nh][ni] = bias[col0 + nh * 128 + wn * 32 + ni * 16 + fr];
    #pragma unroll
    for (int h = 0; h < 2; ++h)
      #pragma unroll
      for (int mi = 0; mi < 4; ++mi)
        #pragma unroll
        for (int j = 0; j < 4; ++j) {
          long rr = row0 + h * 128 + wm * 64 + mi * 16 + fg * 4 + j;
          #pragma unroll
          for (int nh = 0; nh < 2; ++nh)
            #pragma unroll
            for (int ni = 0; ni < 2; ++ni) {
              long cc = col0 + nh * 128 + wn * 32 + ni * 16 + fr;
              float v = acc[h * 4 + mi][nh * 2 + ni][j] + bs[nh][ni];
              if (EPI == 1) v = gelu_t(v);
              outB[rr * N + cc] = __float2bfloat16(v);
            }
        }
    return;
  }

  // EPI 2/3: LDS-transposed f32 epilogue in 4 groups of 64 rows
  __syncthreads();
  float* ep = (float*)&lds[0][0];          // 64*260*4 = 66.6 KB (< 128 KB)
  const int c64 = tid & 63, r8 = tid >> 6;
  const f32x4 b4 = *(const f32x4*)&bias[col0 + c64 * 4];
  #pragma unroll
  for (int g = 0; g < 4; ++g) {
    int h = g >> 1, wmg = g & 1;
    if (wm == wmg) {
      #pragma unroll
      for (int mi = 0; mi < 4; ++mi)
        #pragma unroll
        for (int nh = 0; nh < 2; ++nh)
          #pragma unroll
          for (int ni = 0; ni < 2; ++ni)
            #pragma unroll
            for (int j = 0; j < 4; ++j)
              ep[(mi * 16 + fg * 4 + j) * 260 + nh * 128 + wn * 32 + ni * 16 + fr] =
                  acc[h * 4 + mi][nh * 2 + ni][j];
    }
    __syncthreads();
    #pragma unroll
    for (int it = 0; it < 8; ++it) {
      int lrow = it * 8 + r8;
      long rr = row0 + h * 128 + wmg * 64 + lrow;
      f32x4 v = *(const f32x4*)&ep[lrow * 260 + c64 * 4];
      v += b4;
      if (EPI == 2) {
        int grow = rowOffset + (int)rr;
        int ii = grow % NTOK;
        if (ii != 64) {
          int wb = grow / NTOK;
          int b = wb >> 6, w = wb & 63;
          int wh = w >> 3, ww = w & 7, ih = ii >> 3, iw = ii & 7;
          int hh   = ((wh * 8 + ih) + 4) & 63;
          int wcol = ((ww * 8 + iw) + 4) & 63;
          long o = ((long)b * 4096 + hh * 64 + wcol) * 512 + col0 + c64 * 4;
          f32x4 xi = *(const f32x4*)&xinF[o];
          f32x4 x1 = xi + v;
          short4_t s4;
          #pragma unroll
          for (int e = 0; e < 4; ++e) s4[e] = f2s(x1[e]);
          *(short4_t*)&outB[o] = s4;       // x1b (bf16)
        }
      } else {
        long o = rr * N + col0 + c64 * 4;
        short4_t xv = *(const short4_t*)&xinB[o];
        f32x4 xf;
        #pragma unroll
        for (int e = 0; e < 4; ++e) xf[e] = b2f(xv[e]);
        *(f32x4*)&outF[o] = xf + v;        // final out (f32)
      }
    }
    __syncthreads();
  }
}

// ---------------- 128x128 fallback GEMM (r16, proven) ----------------
template<int EPI, int K>
__global__ __launch_bounds__(256, 3) void gemmk_kernel(
    const bf16* __restrict__ A, const bf16* __restrict__ Bt,
    const float* __restrict__ bias, int N, int nx,
    bf16* __restrict__ outB, float* __restrict__ outF,
    const float* __restrict__ xinF, const bf16* __restrict__ xinB, int rowOffset)
{
  constexpr int NKT = K / 32;
  static_assert((NKT - 1) % 3 == 0, "triplet peel needs NKT = 3m+1");
  __shared__ bf16 ldsbuf[6 * 128 * 32];
  bf16* const lAp = ldsbuf;
  bf16* const lBp = ldsbuf + 3 * 4096;
  const int tid = threadIdx.x;
  const int lane = tid & 63, wv = tid >> 6;
  const int wm = wv >> 1, wn = wv & 1;
  const int fr = lane & 15, fg = lane >> 4;

  const int nwg = gridDim.x, bid = blockIdx.x;
  const int q8 = nwg >> 3, rr8 = nwg & 7;
  const int xcd = bid & 7, idx = bid >> 3;
  const int sid = (xcd < rr8 ? xcd * (q8 + 1) : rr8 * (q8 + 1) + (xcd - rr8) * q8) + idx;
  const long row0 = (long)(sid / nx) * 128;
  const long col0 = (long)(sid % nx) * 128;

  const int rl = lane >> 2, sp = lane & 3;
  const int s = sp ^ ((rl >> 1) & 3);
  const bf16* ga0 = A  + (row0 + wv * 32 + rl) * (long)K + s * 8;
  const bf16* ga1 = ga0 + 16 * (long)K;
  const bf16* gb0 = Bt + (col0 + wv * 32 + rl) * (long)K + s * 8;
  const bf16* gb1 = gb0 + 16 * (long)K;

  f32x4 acc[4][4] = {};
  const int swr = (fg ^ ((fr >> 1) & 3)) << 4;

  auto stage = [&](int buf, int t) {
    const long o = (long)t * 32;
    async_lds16(ga0 + o, &lAp[buf * 4096 + (wv * 32) * 32]);
    async_lds16(ga1 + o, &lAp[buf * 4096 + (wv * 32 + 16) * 32]);
    async_lds16(gb0 + o, &lBp[buf * 4096 + (wv * 32) * 32]);
    async_lds16(gb1 + o, &lBp[buf * 4096 + (wv * 32 + 16) * 32]);
  };

  stage(0, 0);
  stage(1, 1);

#define GBODY(BUF)                                                              \
  do {                                                                          \
    if (t + 1 < NKT) asm volatile("s_waitcnt vmcnt(4)" ::: "memory");           \
    else             asm volatile("s_waitcnt vmcnt(0)" ::: "memory");           \
    __builtin_amdgcn_s_barrier();                                               \
    short8 bfv[4], af[4];                                                       \
    _Pragma("unroll")                                                           \
    for (int ni = 0; ni < 4; ++ni)                                              \
      bfv[ni] = *(const short8*)((const char*)&lBp[(BUF) * 4096] +              \
                                 (wn * 64 + ni * 16 + fr) * 64 + swr);          \
    _Pragma("unroll")                                                           \
    for (int mi = 0; mi < 4; ++mi)                                              \
      af[mi] = *(const short8*)((const char*)&lAp[(BUF) * 4096] +               \
                                (wm * 64 + mi * 16 + fr) * 64 + swr);           \
    if (t + 2 < NKT) stage(((BUF) + 2) % 3, t + 2);                             \
    __builtin_amdgcn_s_setprio(1);                                              \
    _Pragma("unroll")                                                           \
    for (int mi = 0; mi < 4; ++mi)                                              \
      _Pragma("unroll")                                                         \
      for (int ni = 0; ni < 4; ++ni)                                            \
        acc[mi][ni] = __builtin_amdgcn_mfma_f32_16x16x32_bf16(                  \
            af[mi], bfv[ni], acc[mi][ni], 0, 0, 0);                             \
    __builtin_amdgcn_s_setprio(0);                                              \
    ++t;                                                                        \
  } while (0)

  int t = 0;
  GBODY(0);
  for (int g = 0; g < (NKT - 1) / 3; ++g) {
    GBODY(1);
    GBODY(2);
    GBODY(0);
  }
#undef GBODY

  if (EPI == 2 || EPI == 3) {
    __syncthreads();
    float* ep = (float*)ldsbuf;
    const int l31 = lane & 31, lr2 = lane >> 5;
    const f32x4 b4 = *(const f32x4*)&bias[col0 + l31 * 4];
    #pragma unroll
    for (int h = 0; h < 2; ++h) {
      if (wm == h) {
        #pragma unroll
        for (int mi = 0; mi < 4; ++mi)
          #pragma unroll
          for (int ni = 0; ni < 4; ++ni)
            #pragma unroll
            for (int j = 0; j < 4; ++j)
              ep[(mi * 16 + fg * 4 + j) * 132 + wn * 64 + ni * 16 + fr] = acc[mi][ni][j];
      }
      __syncthreads();
      #pragma unroll
      for (int it = 0; it < 8; ++it) {
        int lrow = it * 8 + wv * 2 + lr2;
        long rr = row0 + h * 64 + lrow;
        f32x4 v = *(const f32x4*)&ep[lrow * 132 + l31 * 4];
        v += b4;
        if (EPI == 2) {
          int grow = rowOffset + (int)rr;
          int ii = grow % NTOK;
          if (ii != 64) {
            int wb = grow / NTOK;
            int b = wb >> 6, w = wb & 63;
            int wh = w >> 3, ww = w & 7, ih = ii >> 3, iw = ii & 7;
            int hh   = ((wh * 8 + ih) + 4) & 63;
            int wcol = ((ww * 8 + iw) + 4) & 63;
            long o = ((long)b * 4096 + hh * 64 + wcol) * 512 + col0 + l31 * 4;
            f32x4 xi = *(const f32x4*)&xinF[o];
            f32x4 x1 = xi + v;
            short4_t s4;
            #pragma unroll
            for (int e = 0; e < 4; ++e) s4[e] = f2s(x1[e]);
            *(short4_t*)&outB[o] = s4;
          }
        } else {
          long o = rr * N + col0 + l31 * 4;
          short4_t xv = *(const short4_t*)&xinB[o];
          f32x4 xf;
          #pragma unroll
          for (int e = 0; e < 4; ++e) xf[e] = b2f(xv[e]);
          *(f32x4*)&outF[o] = xf + v;
        }
      }
      __syncthreads();
    }
    return;
  }

  float bs[4];
  #pragma unroll
  for (int ni = 0; ni < 4; ++ni) bs[ni] = bias[col0 + wn * 64 + ni * 16 + fr];
  #pragma unroll
  for (int mi = 0; mi < 4; ++mi) {
    #pragma unroll
    for (int j = 0; j < 4; ++j) {
      long rr = row0 + wm * 64 + mi * 16 + fg * 4 + j;
      #pragma unroll
      for (int ni = 0; ni < 4; ++ni) {
        long cc = col0 + wn * 64 + ni * 16 + fr;
        float v = acc[mi][ni][j] + bs[ni];
        if (EPI == 0) {
          outB[rr * N + cc] = __float2bfloat16(v);
        } else {
          outB[rr * N + cc] = __float2bfloat16(gelu_t(v));
        }
      }
    }
  }
}

// ---------------- MFMA windowed attention: one wave per (window-batch, head) ----
__global__ __launch_bounds__(64, 4) void attn_mfma_kernel(
    const bf16* __restrict__ qkv, bf16* __restrict__ attnO,
    const float* __restrict__ tbl, int wb0)
{
  __shared__ bf16 P[80 * 104];
  const int lwb = blockIdx.x, h = blockIdx.y;
  const int lane = threadIdx.x;
  const int fr = lane & 15, g = lane >> 4;
  const float scale = 0.17677669529663687f;   // 1/sqrt(32)
  const bf16* base = qkv + (long)lwb * 65 * 1536 + h * 32 + g * 8;

  for (int idx = lane; idx < 240; idx += 64) {
    int i = idx / 3, sl = idx % 3;
    *(short8*)&P[i * 104 + 80 + sl * 8] = (short8){0, 0, 0, 0, 0, 0, 0, 0};
  }

  short8 bq[5];
  #pragma unroll
  for (int tn = 0; tn < 5; ++tn) {
    int qr = tn * 16 + fr; qr = qr > 64 ? 64 : qr;
    bq[tn] = *(const short8*)(base + (long)qr * 1536);
  }

  f32x4 acc[5][5];
  #pragma unroll
  for (int tm = 0; tm < 5; ++tm) {
    int kr = tm * 16 + fr; kr = kr > 64 ? 64 : kr;
    short8 ak = *(const short8*)(base + 512 + (long)kr * 1536);
    #pragma unroll
    for (int tn = 0; tn < 5; ++tn)
      acc[tm][tn] = __builtin_amdgcn_mfma_f32_16x16x32_bf16(
          ak, bq[tn], (f32x4){0.0f, 0.0f, 0.0f, 0.0f}, 0, 0, 0);
  }

  const int w = (wb0 + lwb) & 63;
  const int wt = (((w >> 3) == 7) ? 2 : 0) + (((w & 7) == 7) ? 1 : 0);
  const float* tp = tbl + (h * 4 + wt) * 6400;
  #pragma unroll
  for (int tn = 0; tn < 5; ++tn) {
    const int i = tn * 16 + fr;
    const float* ti = tp + i * 80 + g * 4;
    float m = -3.0e38f;
    #pragma unroll
    for (int tm = 0; tm < 5; ++tm) {
      f32x4 bvv = *(const f32x4*)(ti + tm * 16);
      #pragma unroll
      for (int r = 0; r < 4; ++r) {
        float sv = fmaf(acc[tm][tn][r], scale, bvv[r]);
        acc[tm][tn][r] = sv;
        m = fmaxf(m, sv);
      }
    }
    m = fmaxf(m, __shfl_xor(m, 16));
    m = fmaxf(m, __shfl_xor(m, 32));
    float l = 0.0f;
    #pragma unroll
    for (int tm = 0; tm < 5; ++tm)
      #pragma unroll
      for (int r = 0; r < 4; ++r) {
        float e = __expf(acc[tm][tn][r] - m);
        acc[tm][tn][r] = e;
        l += e;
      }
    l += __shfl_xor(l, 16);
    l += __shfl_xor(l, 32);
    float inv = 1.0f / l;
    #pragma unroll
    for (int tm = 0; tm < 5; ++tm) {
      short4_t pk;
      #pragma unroll
      for (int r = 0; r < 4; ++r) pk[r] = f2s(acc[tm][tn][r] * inv);
      *(short4_t*)&P[i * 104 + tm * 16 + g * 4] = pk;
    }
  }

  const bf16* vbase = qkv + (long)lwb * 65 * 1536 + 1024 + h * 32;
  f32x4 oacc[2][5] = {};
  #pragma unroll
  for (int kt = 0; kt < 3; ++kt) {
    short8 bp[5];
    #pragma unroll
    for (int tn = 0; tn < 5; ++tn)
      bp[tn] = *(const short8*)&P[(tn * 16 + fr) * 104 + kt * 32 + g * 8];
    #pragma unroll
    for (int ma = 0; ma < 2; ++ma) {
      short8 av;
      #pragma unroll
      for (int e = 0; e < 8; ++e) {
        int vr = kt * 32 + g * 8 + e; vr = vr > 64 ? 64 : vr;
        av[e] = *(const short*)(vbase + (long)vr * 1536 + ma * 16 + fr);
      }
      #pragma unroll
      for (int tn = 0; tn < 5; ++tn)
        oacc[ma][tn] = __builtin_amdgcn_mfma_f32_16x16x32_bf16(
            av, bp[tn], oacc[ma][tn], 0, 0, 0);
    }
  }

  #pragma unroll
  for (int tn = 0; tn < 5; ++tn) {
    int i = tn * 16 + fr;
    if (i < 65) {
      bf16* op = attnO + (long)(lwb * 65 + i) * 512 + h * 32 + g * 4;
      #pragma unroll
      for (int ma = 0; ma < 2; ++ma) {
        short4_t o4;
        #pragma unroll
        for (int r = 0; r < 4; ++r) o4[r] = f2s(oacc[ma][tn][r]);
        *(short4_t*)(op + ma * 16) = o4;
      }
    }
  }
}

// ---------------- host ----------------

extern "C" void kernel_launch(void* const* d_in, const int* in_sizes, int n_in,
                              void* d_out, int out_size, void* d_ws, size_t ws_size,
                              hipStream_t stream)
{
  const float* x      = (const float*)d_in[0];
  const float* emb    = (const float*)d_in[1];
  const float* gamma1 = (const float*)d_in[2];
  const float* beta1  = (const float*)d_in[3];
  const float* W_emb  = (const float*)d_in[4];
  const float* b_emb  = (const float*)d_in[5];
  const float* W_qkv  = (const float*)d_in[6];
  const float* b_qkv  = (const float*)d_in[7];
  const float* btab   = (const float*)d_in[8];
  const float* W_proj = (const float*)d_in[9];
  const float* b_proj = (const float*)d_in[10];
  const float* gamma2 = (const float*)d_in[11];
  const float* beta2  = (const float*)d_in[12];
  const float* W1     = (const float*)d_in[13];
  const float* b1     = (const float*)d_in[14];
  const float* W2     = (const float*)d_in[15];
  const float* b2     = (const float*)d_in[16];
  float* out = (float*)d_out;
  (void)n_in; (void)in_sizes; (void)out_size;

  char* ws = (char*)d_ws;
  size_t off = 0;
  auto alloc = [&](size_t bytes) -> char* {
    char* p = ws + off;
    off += (bytes + 255) & ~(size_t)255;
    return p;
  };
  bf16* wt_qkv  = (bf16*)alloc((size_t)1536 * 512 * 2);
  bf16* wt_proj = (bf16*)alloc((size_t)512 * 512 * 2);
  bf16* wt1     = (bf16*)alloc((size_t)2048 * 512 * 2);
  bf16* wt2     = (bf16*)alloc((size_t)512 * 2048 * 2);
  float* tvec   = (float*)alloc((size_t)16 * 512 * 4);
  float* tbl    = (float*)alloc((size_t)16 * 4 * 6400 * 4);

  const size_t sz_xw    = (size_t)TOTROWS * 512 * 2;
  const size_t sz_qkv   = (size_t)TOTROWS * 1536 * 2;
  const size_t sz_attnO = (size_t)TOTROWS * 512 * 2;
  const bool big = ws_size >= off + sz_xw + sz_qkv + sz_attnO + (4u << 20);

  transpose_cast_kernel<<<dim3(1536 / 32, 512 / 32), dim3(32, 8), 0, stream>>>(W_qkv, wt_qkv, 512, 1536);
  transpose_cast_kernel<<<dim3(512 / 32, 512 / 32),  dim3(32, 8), 0, stream>>>(W_proj, wt_proj, 512, 512);
  transpose_cast_kernel<<<dim3(2048 / 32, 512 / 32), dim3(32, 8), 0, stream>>>(W1, wt1, 512, 2048);
  transpose_cast_kernel<<<dim3(512 / 32, 2048 / 32), dim3(32, 8), 0, stream>>>(W2, wt2, 2048, 512);
  time_emb_kernel<<<dim3(16, 2), 256, 0, stream>>>(emb, W_emb, b_emb, tvec);
  bias_mask_kernel<<<dim3(16, 4), 256, 0, stream>>>(btab, tbl);

  if (big) {
    char* regionA = alloc(sz_xw);       // xw -> later x1b
    char* regionQ = alloc(sz_qkv);      // qkv -> later h_c + ln2b
    bf16* attnO   = (bf16*)alloc(sz_attnO);
    bf16* xw   = (bf16*)regionA;
    bf16* x1b  = (bf16*)regionA;
    bf16* qkv  = (bf16*)regionQ;
    bf16* h_c  = (bf16*)regionQ;
    bf16* ln2b = (bf16*)(regionQ + (size_t)32768 * 2048 * 2);

    ln1_window_kernel<<<TOTROWS / 4, 256, 0, stream>>>(x, gamma1, beta1, tvec, xw);
    // qkv: M=66560 (260x256), N=1536 (6x256), K=512
    gemm8p_kernel<0, 512><<<6 * 260, 512, 0, stream>>>(
        xw, wt_qkv, b_qkv, 1536, 6, qkv, nullptr, nullptr, nullptr, 0);
    attn_mfma_kernel<<<dim3(NB * NWIN, HEADS_), 64, 0, stream>>>(qkv, attnO, tbl, 0);
    // proj: x1b = bf16(x + C), scatter
    gemm8p_kernel<2, 512><<<2 * 260, 512, 0, stream>>>(
        attnO, wt_proj, b_proj, 512, 2, x1b, nullptr, x, nullptr, 0);
    ln2_kernel<<<IMGROWS / 4, 256, 0, stream>>>(x1b, gamma2, beta2, ln2b);
    for (int mc = 0; mc < 2; ++mc) {
      long r0 = (long)mc * 32768;
      gemm8p_kernel<1, 512><<<8 * 128, 512, 0, stream>>>(
          ln2b + r0 * 512, wt1, b1, 2048, 8, h_c, nullptr, nullptr, nullptr, 0);
      gemm8p_kernel<3, 2048><<<2 * 128, 512, 0, stream>>>(
          h_c, wt2, b2, 512, 2, nullptr, out + r0 * 512, nullptr, x1b + r0 * 512, 0);
    }
  } else {
    // chunked fallback (proven gemmk path)
    char* regionA = alloc(sz_xw);
    bf16* xw   = (bf16*)regionA;
    bf16* x1b  = (bf16*)regionA;
    bf16* qkv_c = (bf16*)alloc((size_t)ATT_CHUNK_ROWS * 1536 * 2);
    char* regionB = alloc(sz_attnO);
    bf16* attnO = (bf16*)regionB;
    bf16* ln2b  = (bf16*)regionB;
    bf16* h_c   = (bf16*)alloc((size_t)16384 * 2048 * 2);

    ln1_window_kernel<<<TOTROWS / 4, 256, 0, stream>>>(x, gamma1, beta1, tvec, xw);
    for (int ac = 0; ac < 8; ++ac) {
      long r0 = (long)ac * ATT_CHUNK_ROWS;
      gemmk_kernel<0, 512><<<12 * 65, 256, 0, stream>>>(
          xw + r0 * 512, wt_qkv, b_qkv, 1536, 12, qkv_c, nullptr, nullptr, nullptr, 0);
      attn_mfma_kernel<<<dim3(ATT_CHUNK_WB, HEADS_), 64, 0, stream>>>(
          qkv_c, attnO + r0 * 512, tbl, ac * ATT_CHUNK_WB);
    }
    gemmk_kernel<2, 512><<<4 * 520, 256, 0, stream>>>(
        attnO, wt_proj, b_proj, 512, 4, x1b, nullptr, x, nullptr, 0);
    ln2_kernel<<<IMGROWS / 4, 256, 0, stream>>>(x1b, gamma2, beta2, ln2b);
    for (int mc = 0; mc < 4; ++mc) {
      long r0 = (long)mc * 16384;
      gemmk_kernel<1, 512><<<16 * 128, 256, 0, stream>>>(
          ln2b + r0 * 512, wt1, b1, 2048, 16, h_c, nullptr, nullptr, nullptr, 0);
      gemmk_kernel<3, 2048><<<4 * 128, 256, 0, stream>>>(
          h_c, wt2, b2, 512, 4, nullptr, out + r0 * 512, nullptr, x1b + r0 * 512, 0);
    }
  }
}